// Round 15
// baseline (2552.037 us; speedup 1.0000x reference)
//
#include <hip/hip_runtime.h>
#include <hip/hip_bf16.h>
#include <math.h>

#define D_    1024
#define H_    16
#define HD_   64
#define L_    14
#define FF_   4096
#define T_    768
#define NPOS_ (2*T_-1)   // 1535

using s16x8 = __attribute__((ext_vector_type(8))) short;
using f32x4 = __attribute__((ext_vector_type(4))) float;

__device__ inline short f2bf(float f) {
  __hip_bfloat16 h = __float2bfloat16(f);
  return *reinterpret_cast<short*>(&h);
}
__device__ inline float bf2f(unsigned short u) {
  union { unsigned u; float f; } v; v.u = ((unsigned)u) << 16; return v.f;
}

// ---------------- reduction helpers ----------------
__device__ inline float waveRedSum(float v) {
#pragma unroll
  for (int o = 32; o > 0; o >>= 1) v += __shfl_down(v, o, 64);
  return v;
}
__device__ inline float blockRedSum(float v, float* sh) {
  int lane = threadIdx.x & 63, wid = threadIdx.x >> 6;
  v = waveRedSum(v);
  if (lane == 0) sh[wid] = v;
  __syncthreads();
  if (wid == 0) {
    float x = (lane < 4) ? sh[lane] : 0.f;
    x = waveRedSum(x);
    if (lane == 0) sh[0] = x;
  }
  __syncthreads();
  float r = sh[0];
  __syncthreads();
  return r;
}

// ---------------- LayerNorm: fp32 in, fp32-or-bf16 out (one-pass stats) ----------------
__global__ __launch_bounds__(256) void ln_kernel(
    const float* __restrict__ x, const float* __restrict__ g,
    const float* __restrict__ b, void* __restrict__ y,
    float eps, int relu, float scale, int obf)
{
  __shared__ float sh[8];
  long row = blockIdx.x;
  const float* xr = x + row * D_;
  int tid = threadIdx.x;
  float4 v = *(const float4*)&xr[tid * 4];
  float s  = v.x + v.y + v.z + v.w;
  float sq = v.x * v.x + v.y * v.y + v.z * v.z + v.w * v.w;
  float mean = blockRedSum(s, sh) * (1.f / D_);
  float esq  = blockRedSum(sq, sh) * (1.f / D_);
  float var  = esq - mean * mean;
  if (var < 0.f) var = 0.f;
  float inv = rsqrtf(var + eps);
  float4 gv = *(const float4*)&g[tid * 4];
  float4 bv = *(const float4*)&b[tid * 4];
  float o0 = (v.x - mean) * inv * gv.x + bv.x;
  float o1 = (v.y - mean) * inv * gv.y + bv.y;
  float o2 = (v.z - mean) * inv * gv.z + bv.z;
  float o3 = (v.w - mean) * inv * gv.w + bv.w;
  if (relu) {
    o0 = fmaxf(o0, 0.f); o1 = fmaxf(o1, 0.f);
    o2 = fmaxf(o2, 0.f); o3 = fmaxf(o3, 0.f);
  }
  o0 *= scale; o1 *= scale; o2 *= scale; o3 *= scale;
  if (obf) {
    short4 sv;
    sv.x = f2bf(o0); sv.y = f2bf(o1); sv.z = f2bf(o2); sv.w = f2bf(o3);
    *(short4*)&((unsigned short*)y)[row * D_ + tid * 4] = sv;
  } else {
    float4 ov; ov.x = o0; ov.y = o1; ov.z = o2; ov.w = o3;
    *(float4*)&((float*)y)[row * D_ + tid * 4] = ov;
  }
}

// ---------------- weight transpose+convert: [K][N] fp32 -> [N][K] bf16 ----------------
__global__ __launch_bounds__(256) void transpose_kernel(
    const float* __restrict__ in, unsigned short* __restrict__ out, int K, int N)
{
  __shared__ unsigned short t[32][33];
  long z = blockIdx.z;
  in  += z * (long)K * N;
  out += z * (long)K * N;
  int n0 = blockIdx.x * 32, k0 = blockIdx.y * 32;
  int tid = threadIdx.x;
  int r = tid >> 3, c4 = (tid & 7) * 4;
  float4 v = *(const float4*)&in[(long)(k0 + r) * N + n0 + c4];
  t[r][c4 + 0] = (unsigned short)f2bf(v.x);
  t[r][c4 + 1] = (unsigned short)f2bf(v.y);
  t[r][c4 + 2] = (unsigned short)f2bf(v.z);
  t[r][c4 + 3] = (unsigned short)f2bf(v.w);
  __syncthreads();
  ushort4 s;
  s.x = t[c4 + 0][r]; s.y = t[c4 + 1][r]; s.z = t[c4 + 2][r]; s.w = t[c4 + 3][r];
  *(ushort4*)&out[(long)(n0 + r) * K + k0 + c4] = s;
}

// merged transpose for the five DxD weight stacks (z = g*L + layer, g in 0..4)
__global__ __launch_bounds__(256) void transpose5_kernel(
    const float* __restrict__ W0, const float* __restrict__ W1,
    const float* __restrict__ W2, const float* __restrict__ W3,
    const float* __restrict__ W4,
    unsigned short* __restrict__ O0, unsigned short* __restrict__ O1,
    unsigned short* __restrict__ O2, unsigned short* __restrict__ O3,
    unsigned short* __restrict__ O4)
{
  __shared__ unsigned short t[32][33];
  int z = blockIdx.z;
  int g = z / L_, zi = z % L_;
  const float* in = (g == 0) ? W0 : (g == 1) ? W1 : (g == 2) ? W2 : (g == 3) ? W3 : W4;
  unsigned short* out = (g == 0) ? O0 : (g == 1) ? O1 : (g == 2) ? O2 : (g == 3) ? O3 : O4;
  in  += (long)zi * D_ * D_;
  out += (long)zi * D_ * D_;
  int n0 = blockIdx.x * 32, k0 = blockIdx.y * 32;
  int tid = threadIdx.x;
  int r = tid >> 3, c4 = (tid & 7) * 4;
  float4 v = *(const float4*)&in[(long)(k0 + r) * D_ + n0 + c4];
  t[r][c4 + 0] = (unsigned short)f2bf(v.x);
  t[r][c4 + 1] = (unsigned short)f2bf(v.y);
  t[r][c4 + 2] = (unsigned short)f2bf(v.z);
  t[r][c4 + 3] = (unsigned short)f2bf(v.w);
  __syncthreads();
  ushort4 s;
  s.x = t[c4 + 0][r]; s.y = t[c4 + 1][r]; s.z = t[c4 + 2][r]; s.w = t[c4 + 3][r];
  *(ushort4*)&out[(long)(n0 + r) * D_ + k0 + c4] = s;
}

// ---------------- gemm8: double-buffered LDS, T14 ordering + T5 setprio ----------------
template<int BM, int BN, bool CBF16>
__global__ __launch_bounds__(256) void gemm8_kernel(
    const unsigned short* __restrict__ A, int lda, long sAz,
    const unsigned short* __restrict__ B0, const unsigned short* __restrict__ B1,
    const unsigned short* __restrict__ B2, int ldb, long sBz,
    void* C0, void* C1, void* C2, int ldc, long sCz,
    const float* __restrict__ bias0, const float* __restrict__ bias1,
    const float* __restrict__ bias2,
    const float* __restrict__ resid, int ldres,
    int M, int N, int K, int zPerG, int relu, int nM)
{
  constexpr int FM = BM / 32, FN = BN / 32;
  constexpr int A_IT = BM / 32;
  constexpr int B_IT = BN / 32;

  __shared__ short As0[BM * 64];
  __shared__ short Bs0[BN * 64];
  __shared__ short As1[BM * 64];
  __shared__ short Bs1[BN * 64];

  int nb = gridDim.x, bid = blockIdx.x;
  int q = nb >> 3, r = nb & 7, xcd = bid & 7, idx = bid >> 3;
  int lbid = (xcd < r ? xcd * (q + 1) : r * (q + 1) + (xcd - r) * q) + idx;
  int mT = lbid % nM, nT = lbid / nM;
  int m0 = mT * BM, n0 = nT * BN;

  int z = blockIdx.z;
  int g = z / zPerG, zb = z - g * zPerG;
  A += (long)zb * sAz;
  const unsigned short* Bh = ((g == 0) ? B0 : ((g == 1) ? B1 : B2)) + zb * sBz;
  void* Cv = (g == 0) ? C0 : ((g == 1) ? C1 : C2);
  const float* bias = (g == 0) ? bias0 : ((g == 1) ? bias1 : bias2);
  float* Cf = (float*)Cv + zb * sCz;
  unsigned short* Ch = (unsigned short*)Cv + zb * sCz;

  int tid = threadIdx.x, lane = tid & 63, wid = tid >> 6;
  int wm0 = (wid >> 1) * (BM / 2), wn0 = (wid & 1) * (BN / 2);
  int lr = lane & 15, kl = (lane >> 4) * 8;

  f32x4 acc[FM][FN];
#pragma unroll
  for (int i = 0; i < FM; ++i)
#pragma unroll
    for (int j = 0; j < FN; ++j)
#pragma unroll
      for (int rr = 0; rr < 4; ++rr) acc[i][j][rr] = 0.f;

  s16x8 ar[A_IT], br[B_IT];

  auto loadT = [&](int k0) {
#pragma unroll
    for (int it = 0; it < A_IT; ++it) {
      int f = tid + it * 256;
      int row = f >> 3, c8 = f & 7;
      int gm = m0 + row;
      s16x8 v = {0, 0, 0, 0, 0, 0, 0, 0};
      if (gm < M) v = *(const s16x8*)(A + (long)gm * lda + k0 + c8 * 8);
      ar[it] = v;
    }
#pragma unroll
    for (int it = 0; it < B_IT; ++it) {
      int f = tid + it * 256;
      int row = f >> 3, c8 = f & 7;
      br[it] = *(const s16x8*)(Bh + (long)(n0 + row) * ldb + k0 + c8 * 8);
    }
  };
  auto writeT = [&](short* as, short* bs) {
#pragma unroll
    for (int it = 0; it < A_IT; ++it) {
      int f = tid + it * 256;
      int row = f >> 3, c8 = f & 7;
      *(s16x8*)&as[row * 64 + ((c8 ^ (row & 7)) << 3)] = ar[it];
    }
#pragma unroll
    for (int it = 0; it < B_IT; ++it) {
      int f = tid + it * 256;
      int row = f >> 3, c8 = f & 7;
      *(s16x8*)&bs[row * 64 + ((c8 ^ (row & 7)) << 3)] = br[it];
    }
  };
  auto compute = [&](const short* as, const short* bs) {
#pragma unroll
    for (int kk = 0; kk < 2; ++kk) {
      s16x8 a[FM], b[FN];
#pragma unroll
      for (int i = 0; i < FM; ++i) {
        int row = wm0 + i * 16 + lr;
        a[i] = *(const s16x8*)&as[row * 64 + ((kk * 32 + kl) ^ ((lr & 7) << 3))];
      }
#pragma unroll
      for (int j = 0; j < FN; ++j) {
        int row = wn0 + j * 16 + lr;
        b[j] = *(const s16x8*)&bs[row * 64 + ((kk * 32 + kl) ^ ((lr & 7) << 3))];
      }
      __builtin_amdgcn_s_setprio(1);
#pragma unroll
      for (int i = 0; i < FM; ++i)
#pragma unroll
        for (int j = 0; j < FN; ++j)
          acc[i][j] = __builtin_amdgcn_mfma_f32_16x16x32_bf16(a[i], b[j], acc[i][j], 0, 0, 0);
      __builtin_amdgcn_s_setprio(0);
    }
  };

  int nt = K / 64;                     // even
  loadT(0);
  writeT(As0, Bs0);
  __syncthreads();
  for (int t = 0; t < nt; t += 2) {
    loadT((t + 1) * 64);
    compute(As0, Bs0);
    writeT(As1, Bs1);
    __syncthreads();
    if (t + 2 < nt) loadT((t + 2) * 64);
    compute(As1, Bs1);
    if (t + 2 < nt) writeT(As0, Bs0);
    __syncthreads();
  }

#pragma unroll
  for (int i = 0; i < FM; ++i) {
#pragma unroll
    for (int j = 0; j < FN; ++j) {
      int n = n0 + wn0 + j * 16 + lr;
      float bv = bias ? bias[n] : 0.f;
#pragma unroll
      for (int rr = 0; rr < 4; ++rr) {
        int m = m0 + wm0 + i * 16 + (lane >> 4) * 4 + rr;
        if (m < M) {
          float v = acc[i][j][rr] + bv;
          if (resid) v += resid[(long)m * ldres + n];
          if (relu)  v = fmaxf(v, 0.f);
          if constexpr (CBF16) Ch[(long)m * ldc + n] = (unsigned short)f2bf(v);
          else                 Cf[(long)m * ldc + n] = v;
        }
      }
    }
  }
}

// ---------------- LDS GEMM v5 (fallback, fp32 B, single-buffered) ----------------
template<int BM, int BN, bool CBF16>
__global__ __launch_bounds__(256) void gemm5_kernel(
    const unsigned short* __restrict__ A, int lda, long sAz,
    const void* __restrict__ B0, const void* __restrict__ B1, const void* __restrict__ B2,
    int ldb, long sBz,
    void* C0, void* C1, void* C2, int ldc, long sCz,
    const float* __restrict__ bias0, const float* __restrict__ bias1,
    const float* __restrict__ bias2,
    const float* __restrict__ resid, int ldres,
    int M, int N, int K, int zPerG, int relu, int nM)
{
  constexpr int FM = BM / 32, FN = BN / 32;
  constexpr int A_IT = BM / 32;
  constexpr int NSH = (BN == 128) ? 7 : 6;

  __shared__ short As[BM * 64];
  __shared__ short Bs[BN * 64];

  int nb = gridDim.x, bid = blockIdx.x;
  int q = nb >> 3, r = nb & 7, xcd = bid & 7, idx = bid >> 3;
  int lbid = (xcd < r ? xcd * (q + 1) : r * (q + 1) + (xcd - r) * q) + idx;
  int mT = lbid % nM, nT = lbid / nM;
  int m0 = mT * BM, n0 = nT * BN;

  int z = blockIdx.z;
  int g = z / zPerG, zb = z - g * zPerG;
  A += (long)zb * sAz;
  const void* Bv = (g == 0) ? B0 : ((g == 1) ? B1 : B2);
  void* Cv       = (g == 0) ? C0 : ((g == 1) ? C1 : C2);
  const float* bias = (g == 0) ? bias0 : ((g == 1) ? bias1 : bias2);
  const float* Bf = (const float*)Bv + zb * sBz;
  float* Cf = (float*)Cv + zb * sCz;
  unsigned short* Ch = (unsigned short*)Cv + zb * sCz;

  int tid = threadIdx.x, lane = tid & 63, wid = tid >> 6;
  int wm0 = (wid >> 1) * (BM / 2), wn0 = (wid & 1) * (BN / 2);
  int lr = lane & 15, kl = (lane >> 4) * 8;

  f32x4 acc[FM][FN];
#pragma unroll
  for (int i = 0; i < FM; ++i)
#pragma unroll
    for (int j = 0; j < FN; ++j)
#pragma unroll
      for (int rr = 0; rr < 4; ++rr) acc[i][j][rr] = 0.f;

  for (int k0 = 0; k0 < K; k0 += 64) {
#pragma unroll
    for (int it = 0; it < A_IT; ++it) {
      int f = tid + it * 256;
      int row = f >> 3, c8 = f & 7;
      int gm = m0 + row;
      s16x8 v = {0, 0, 0, 0, 0, 0, 0, 0};
      if (gm < M) v = *(const s16x8*)(A + (long)gm * lda + k0 + c8 * 8);
      *(s16x8*)&As[row * 64 + ((c8 ^ (row & 7)) << 3)] = v;
    }
    constexpr int B_IT2 = BN / 16;
#pragma unroll
    for (int it = 0; it < B_IT2; ++it) {
      int p = tid + it * 256;
      int n = p & (BN - 1), kq = p >> NSH;
      int gn = n0 + n;
      const float* bp = Bf + (long)(k0 + kq * 4) * ldb + gn;
      short4 s;
      s.x = f2bf(bp[0]); s.y = f2bf(bp[ldb]);
      s.z = f2bf(bp[2 * (long)ldb]); s.w = f2bf(bp[3 * (long)ldb]);
      *(short4*)&Bs[n * 64 + ((kq << 2) ^ ((n & 7) << 3))] = s;
    }
    __syncthreads();
#pragma unroll
    for (int kk = 0; kk < 2; ++kk) {
      s16x8 a[FM], b[FN];
#pragma unroll
      for (int i = 0; i < FM; ++i) {
        int row = wm0 + i * 16 + lr;
        a[i] = *(const s16x8*)&As[row * 64 + ((kk * 32 + kl) ^ ((lr & 7) << 3))];
      }
#pragma unroll
      for (int j = 0; j < FN; ++j) {
        int row = wn0 + j * 16 + lr;
        b[j] = *(const s16x8*)&Bs[row * 64 + ((kk * 32 + kl) ^ ((lr & 7) << 3))];
      }
#pragma unroll
      for (int i = 0; i < FM; ++i)
#pragma unroll
        for (int j = 0; j < FN; ++j)
          acc[i][j] = __builtin_amdgcn_mfma_f32_16x16x32_bf16(a[i], b[j], acc[i][j], 0, 0, 0);
    }
    __syncthreads();
  }
#pragma unroll
  for (int i = 0; i < FM; ++i) {
#pragma unroll
    for (int j = 0; j < FN; ++j) {
      int n = n0 + wn0 + j * 16 + lr;
      float bv = bias ? bias[n] : 0.f;
#pragma unroll
      for (int rr = 0; rr < 4; ++rr) {
        int m = m0 + wm0 + i * 16 + (lane >> 4) * 4 + rr;
        if (m < M) {
          float v = acc[i][j][rr] + bv;
          if (resid) v += resid[(long)m * ldres + n];
          if (relu)  v = fmaxf(v, 0.f);
          if constexpr (CBF16) Ch[(long)m * ldc + n] = (unsigned short)f2bf(v);
          else                 Cf[(long)m * ldc + n] = v;
        }
      }
    }
  }
}

// ---------------- fp32 -> bf16 convert ----------------
__global__ __launch_bounds__(256) void f2bf_kernel(
    const float* __restrict__ x, unsigned short* __restrict__ y, int n4)
{
  int i = blockIdx.x * 256 + threadIdx.x;
  if (i >= n4) return;
  float4 v = *(const float4*)&x[i * 4];
  short4 s; s.x = f2bf(v.x); s.y = f2bf(v.y); s.z = f2bf(v.z); s.w = f2bf(v.w);
  *(short4*)&y[i * 4] = s;
}

// ---------------- relative positional encoding table (bf16) ----------------
__global__ __launch_bounds__(256) void pos_kernel(unsigned short* __restrict__ pos)
{
  int idx = blockIdx.x * 256 + threadIdx.x;
  if (idx >= NPOS_ * (D_ / 2)) return;
  int n = idx / (D_ / 2), i = idx % (D_ / 2);
  float r = (float)(T_ - 1 - n);
  float div = __expf((float)(2 * i) * (-logf(10000.f) / (float)D_));
  float ang = r * div;
  pos[(long)n * D_ + 2 * i]     = (unsigned short)f2bf(sinf(ang));
  pos[(long)n * D_ + 2 * i + 1] = (unsigned short)f2bf(cosf(ang));
}

// ---------------- fused flash attention with rel-shift (R12 + coalesced V staging) ----------------
__global__ __launch_bounds__(256) void flash_attn_kernel(
    const unsigned short* __restrict__ Q, const unsigned short* __restrict__ K,
    const unsigned short* __restrict__ V, const unsigned short* __restrict__ P,
    const float* __restrict__ posu, const float* __restrict__ posv,
    unsigned short* __restrict__ O)
{
  __shared__ short Ks[64 * 64];
  __shared__ short Vs[64 * 64];
  __shared__ short Ps[96 * 64];
  __shared__ float Grgn[32 * 99];
  __shared__ float mxls[2][32], smls[2][32];

  short* qu = (short*)Grgn;
  short* qv = qu + 32 * 64;
  float* G  = Grgn;
  short* Pf = (short*)Grgn;

  int h = blockIdx.y;
  int t0 = blockIdx.x * 32;
  int tid = threadIdx.x, lane = tid & 63, w = tid >> 6;
  int wr = w >> 1, wc = w & 1;
  int lr = lane & 15, lg = lane >> 4;
  int kl = lg * 8;
  const float* pu = posu + h * HD_;
  const float* pv = posv + h * HD_;

  {
    int row = tid >> 3, c8 = tid & 7;
    s16x8 q8 = *(const s16x8*)(Q + (long)(t0 + row) * D_ + h * HD_ + c8 * 8);
    const unsigned short* qp = (const unsigned short*)&q8;
    s16x8 su, sv;
#pragma unroll
    for (int j = 0; j < 8; ++j) {
      float qf = bf2f(qp[j]);
      su[j] = f2bf(qf + pu[c8 * 8 + j]);
      sv[j] = f2bf(qf + pv[c8 * 8 + j]);
    }
    int sw = row * 64 + ((c8 ^ (row & 7)) << 3);
    *(s16x8*)&qu[sw] = su;
    *(s16x8*)&qv[sw] = sv;
  }
  __syncthreads();
  s16x8 aqu[2], aqv[2];
#pragma unroll
  for (int kk = 0; kk < 2; ++kk) {
    int row = wr * 16 + lr;
    int col = (kk * 32 + kl) ^ ((lr & 7) << 3);
    aqu[kk] = *(const s16x8*)&qu[row * 64 + col];
    aqv[kk] = *(const s16x8*)&qv[row * 64 + col];
  }

  float m_[4], l_[4];
  f32x4 acc_o[2];
#pragma unroll
  for (int rr = 0; rr < 4; ++rr) { m_[rr] = -1e30f; l_[rr] = 0.f; }
#pragma unroll
  for (int j = 0; j < 2; ++j)
#pragma unroll
    for (int rr = 0; rr < 4; ++rr) acc_o[j][rr] = 0.f;

  for (int s0 = 0; s0 < T_; s0 += 64) {
    int base = s0 - t0 + T_ - 32;
    __syncthreads();
    // ---- stage K (16B coalesced) ----
#pragma unroll
    for (int it = 0; it < 2; ++it) {
      int f = tid + it * 256;
      int row = f >> 3, c8 = f & 7;
      s16x8 v = *(const s16x8*)(K + (long)(s0 + row) * D_ + h * HD_ + c8 * 8);
      *(s16x8*)&Ks[row * 64 + ((c8 ^ (row & 7)) << 3)] = v;
    }
    // ---- stage V^T: coalesced 16B row loads + transpose-scatter u16 writes ----
#pragma unroll
    for (int it = 0; it < 2; ++it) {
      int f = tid + it * 256;
      int s = f >> 3, c8 = f & 7;
      s16x8 v = *(const s16x8*)(V + (long)(s0 + s) * D_ + h * HD_ + c8 * 8);
#pragma unroll
      for (int e = 0; e < 8; ++e) {
        int d = c8 * 8 + e;
        Vs[d * 64 + (s ^ ((d & 7) << 3))] = v[e];
      }
    }
    // ---- stage P (16B coalesced) ----
#pragma unroll
    for (int it = 0; it < 3; ++it) {
      int f = tid + it * 256;
      int row = f >> 3, c8 = f & 7;
      int gp = base + row; if (gp > NPOS_ - 1) gp = NPOS_ - 1;
      s16x8 v = *(const s16x8*)(P + (long)gp * D_ + h * HD_ + c8 * 8);
      *(s16x8*)&Ps[row * 64 + ((c8 ^ (row & 7)) << 3)] = v;
    }
    __syncthreads();
    f32x4 a_ac[2], a_g[3];
#pragma unroll
    for (int j = 0; j < 2; ++j)
#pragma unroll
      for (int rr = 0; rr < 4; ++rr) a_ac[j][rr] = 0.f;
#pragma unroll
    for (int j = 0; j < 3; ++j)
#pragma unroll
      for (int rr = 0; rr < 4; ++rr) a_g[j][rr] = 0.f;
#pragma unroll
    for (int j = 0; j < 2; ++j)
#pragma unroll
      for (int kk = 0; kk < 2; ++kk) {
        int row = wc * 32 + j * 16 + lr;
        s16x8 b = *(const s16x8*)&Ks[row * 64 + ((kk * 32 + kl) ^ ((lr & 7) << 3))];
        a_ac[j] = __builtin_amdgcn_mfma_f32_16x16x32_bf16(aqu[kk], b, a_ac[j], 0, 0, 0);
      }
#pragma unroll
    for (int j = 0; j < 3; ++j)
#pragma unroll
      for (int kk = 0; kk < 2; ++kk) {
        int row = wc * 48 + j * 16 + lr;
        s16x8 b = *(const s16x8*)&Ps[row * 64 + ((kk * 32 + kl) ^ ((lr & 7) << 3))];
        a_g[j] = __builtin_amdgcn_mfma_f32_16x16x32_bf16(aqv[kk], b, a_g[j], 0, 0, 0);
      }
#pragma unroll
    for (int j = 0; j < 3; ++j)
#pragma unroll
      for (int rr = 0; rr < 4; ++rr) {
        int row = wr * 16 + lg * 4 + rr;
        int col = wc * 48 + j * 16 + lr;
        G[row * 99 + col] = a_g[j][rr];
      }
    __syncthreads();
    float sreg[2][4], pm[4];
#pragma unroll
    for (int rr = 0; rr < 4; ++rr) {
      int row = wr * 16 + lg * 4 + rr;
#pragma unroll
      for (int j = 0; j < 2; ++j) {
        int c = wc * 32 + j * 16 + lr;
        int gc = c - row + 31;
        sreg[j][rr] = (a_ac[j][rr] + G[row * 99 + gc]) * 0.125f;
      }
      pm[rr] = fmaxf(sreg[0][rr], sreg[1][rr]);
    }
#pragma unroll
    for (int o = 1; o < 16; o <<= 1)
#pragma unroll
      for (int rr = 0; rr < 4; ++rr) pm[rr] = fmaxf(pm[rr], __shfl_xor(pm[rr], o, 64));
    if (lr == 0) {
#pragma unroll
      for (int rr = 0; rr < 4; ++rr) mxls[wc][wr * 16 + lg * 4 + rr] = pm[rr];
    }
    __syncthreads();
    float ps[4];
#pragma unroll
    for (int rr = 0; rr < 4; ++rr) {
      int row = wr * 16 + lg * 4 + rr;
      float mnew = fmaxf(m_[rr], fmaxf(mxls[0][row], mxls[1][row]));
      float sc = __expf(m_[rr] - mnew);
      m_[rr] = mnew;
      l_[rr] *= sc;
      acc_o[0][rr] *= sc;
      acc_o[1][rr] *= sc;
      float p0 = __expf(sreg[0][rr] - mnew);
      float p1 = __expf(sreg[1][rr] - mnew);
      ps[rr] = p0 + p1;
      int c0 = wc * 32 + lr, c1 = wc * 32 + 16 + lr;
      ((unsigned short*)Pf)[row * 64 + (c0 ^ ((row & 7) << 3))] = (unsigned short)f2bf(p0);
      ((unsigned short*)Pf)[row * 64 + (c1 ^ ((row & 7) << 3))] = (unsigned short)f2bf(p1);
    }
#pragma unroll
    for (int o = 1; o < 16; o <<= 1)
#pragma unroll
      for (int rr = 0; rr < 4; ++rr) ps[rr] += __shfl_xor(ps[rr], o, 64);
    if (lr == 0) {
#pragma unroll
      for (int rr = 0; rr < 4; ++rr) smls[wc][wr * 16 + lg * 4 + rr] = ps[rr];
    }
    __syncthreads();
#pragma unroll
    for (int rr = 0; rr < 4; ++rr) {
      int row = wr * 16 + lg * 4 + rr;
      l_[rr] += smls[0][row] + smls[1][row];
    }
    s16x8 ap[2];
#pragma unroll
    for (int kk = 0; kk < 2; ++kk) {
      int row = wr * 16 + lr;
      ap[kk] = *(const s16x8*)&((unsigned short*)Pf)[row * 64 + ((kk * 32 + kl) ^ ((lr & 7) << 3))];
    }
#pragma unroll
    for (int j = 0; j < 2; ++j)
#pragma unroll
      for (int kk = 0; kk < 2; ++kk) {
        int row = wc * 32 + j * 16 + lr;
        s16x8 b = *(const s16x8*)&Vs[row * 64 + ((kk * 32 + kl) ^ ((lr & 7) << 3))];
        acc_o[j] = __builtin_amdgcn_mfma_f32_16x16x32_bf16(ap[kk], b, acc_o[j], 0, 0, 0);
      }
  }
#pragma unroll
  for (int j = 0; j < 2; ++j)
#pragma unroll
    for (int rr = 0; rr < 4; ++rr) {
      int row = t0 + wr * 16 + lg * 4 + rr;
      int col = h * HD_ + wc * 32 + j * 16 + lr;
      O[(long)row * D_ + col] = (unsigned short)f2bf(acc_o[j][rr] / l_[rr]);
    }
}

// ---------------- host side ----------------
extern "C" void kernel_launch(void* const* d_in, const int* in_sizes, int n_in,
                              void* d_out, int out_size, void* d_ws, size_t ws_size,
                              hipStream_t stream) {
  const float* xs       = (const float*)d_in[0];
  const float* embed_W  = (const float*)d_in[1];
  const float* embed_b  = (const float*)d_in[2];
  const float* embed_g  = (const float*)d_in[3];
  const float* embed_bt = (const float*)d_in[4];
  const float* Wq = (const float*)d_in[5];
  const float* bq = (const float*)d_in[6];
  const float* Wk = (const float*)d_in[7];
  const float* bk = (const float*)d_in[8];
  const float* Wv = (const float*)d_in[9];
  const float* bv = (const float*)d_in[10];
  const float* Wo = (const float*)d_in[11];
  const float* bo = (const float*)d_in[12];
  const float* Wp = (const float*)d_in[13];
  const float* pos_u = (const float*)d_in[14];
  const float* pos_v = (const float*)d_in[15];
  const float* ln1_g = (const float*)d_in[16];
  const float* ln1_b = (const float*)d_in[17];
  const float* ln2_g = (const float*)d_in[18];
  const float* ln2_b = (const float*)d_in[19];
  const float* ff_W1 = (const float*)d_in[20];
  const float* ff_b1 = (const float*)d_in[21];
  const float* ff_W2 = (const float*)d_in[22];
  const float* ff_b2 = (const float*)d_in[23];
  const float* after_g = (const float*)d_in[24];
  const float* after_b = (const float*)d_in[25];
  float* out = (float*)d_out;

  char* w = (char*)d_ws;
  auto carve = [&](size_t bytes) { char* p = w; w += (bytes + 255) & ~(size_t)255; return p; };
  float* bufX  = (float*)carve((size_t)T_ * D_ * 4);
  float* bufT  = (float*)carve((size_t)T_ * D_ * 4);
  unsigned short* xsb  = (unsigned short*)carve((size_t)T_ * D_ * 2);
  unsigned short* XNb  = (unsigned short*)carve((size_t)T_ * D_ * 2);
  unsigned short* Qb   = (unsigned short*)carve((size_t)T_ * D_ * 2);
  unsigned short* Kb   = (unsigned short*)carve((size_t)T_ * D_ * 2);
  unsigned short* Vb   = (unsigned short*)carve((size_t)T_ * D_ * 2);
  unsigned short* Ob   = (unsigned short*)carve((size_t)T_ * D_ * 2);
  unsigned short* Hb   = (unsigned short*)carve((size_t)T_ * FF_ * 2);
  unsigned short* posT = (unsigned short*)carve((size_t)(NPOS_ + 16) * D_ * 2);
  unsigned short* Pall = (unsigned short*)carve((size_t)L_ * NPOS_ * D_ * 2);
  size_t szDD = (size_t)D_ * D_;
  unsigned short* embedWt = (unsigned short*)carve(szDD * 2);
  unsigned short* WqT = (unsigned short*)carve((size_t)L_ * szDD * 2);
  unsigned short* WkT = (unsigned short*)carve((size_t)L_ * szDD * 2);
  unsigned short* WvT = (unsigned short*)carve((size_t)L_ * szDD * 2);
  unsigned short* WoT = (unsigned short*)carve((size_t)L_ * szDD * 2);
  unsigned short* WpT = (unsigned short*)carve((size_t)L_ * szDD * 2);
  unsigned short* W1T = (unsigned short*)carve((size_t)L_ * D_ * FF_ * 2);
  unsigned short* W2T = (unsigned short*)carve((size_t)L_ * D_ * FF_ * 2);
  bool fast = ((size_t)(w - (char*)d_ws) <= ws_size);

  {
    int n = NPOS_ * (D_ / 2);
    pos_kernel<<<(n + 255) / 256, 256, 0, stream>>>(posT);
  }
  f2bf_kernel<<<(T_ * D_ / 4 + 255) / 256, 256, 0, stream>>>(xs, xsb, T_ * D_ / 4);

  if (fast) {
    transpose_kernel<<<dim3(32, 32, 1),  256, 0, stream>>>(embed_W, embedWt, D_, D_);
    transpose5_kernel<<<dim3(32, 32, 5 * L_), 256, 0, stream>>>(
        Wq, Wk, Wv, Wo, Wp, WqT, WkT, WvT, WoT, WpT);
    transpose_kernel<<<dim3(128, 32, L_), 256, 0, stream>>>(ff_W1, W1T, D_, FF_);
    transpose_kernel<<<dim3(32, 128, L_), 256, 0, stream>>>(ff_W2, W2T, FF_, D_);

    gemm8_kernel<32, 128, false><<<dim3(192, 1, 1), 256, 0, stream>>>(
        xsb, D_, 0, embedWt, nullptr, nullptr, D_, 0,
        bufT, nullptr, nullptr, D_, 0, embed_b, nullptr, nullptr,
        nullptr, 0, T_, D_, D_, 1, 0, 24);
    ln_kernel<<<T_, 256, 0, stream>>>(bufT, embed_g, embed_bt, bufX, 1e-5f, 1, 32.0f, 0);

    gemm8_kernel<128, 64, true><<<dim3(192, 1, 14), 256, 0, stream>>>(
        posT, D_, 0, WpT, nullptr, nullptr, D_, (long)szDD,
        Pall, nullptr, nullptr, D_, (long)NPOS_ * D_, nullptr, nullptr, nullptr,
        nullptr, 0, NPOS_, D_, D_, 14, 0, 12);

    for (int i = 0; i < L_; ++i) {
      ln_kernel<<<T_, 256, 0, stream>>>(bufX, ln1_g + (long)i * D_, ln1_b + (long)i * D_,
                                        XNb, 1e-12f, 0, 1.0f, 1);
      gemm8_kernel<64, 128, true><<<dim3(96, 1, 3), 256, 0, stream>>>(
          XNb, D_, 0, WqT + i * szDD, WkT + i * szDD, WvT + i * szDD, D_, 0,
          Qb, Kb, Vb, D_, 0,
          bq + (long)i * D_, bk + (long)i * D_, bv + (long)i * D_,
          nullptr, 0, T_, D_, D_, 1, 0, 12);
      flash_attn_kernel<<<dim3(T_ / 32, H_), 256, 0, stream>>>(
          Qb, Kb, Vb, Pall + (long)i * NPOS_ * D_,
          pos_u + (long)i * D_, pos_v + (long)i * D_, Ob);
      gemm8_kernel<32, 64, false><<<dim3(384, 1, 1), 256, 0, stream>>>(
          Ob, D_, 0, WoT + i * szDD, nullptr, nullptr, D_, 0,
          bufX, nullptr, nullptr, D_, 0, bo + (long)i * D_, nullptr, nullptr,
          bufX, D_, T_, D_, D_, 1, 0, 24);
      ln_kernel<<<T_, 256, 0, stream>>>(bufX, ln2_g + (long)i * D_, ln2_b + (long)i * D_,
                                        XNb, 1e-12f, 0, 1.0f, 1);
      gemm8_kernel<64, 128, true><<<dim3(384, 1, 1), 256, 0, stream>>>(
          XNb, D_, 0, W1T + (size_t)i * D_ * FF_, nullptr, nullptr, D_, 0,
          Hb, nullptr, nullptr, FF_, 0, ff_b1 + (long)i * FF_, nullptr, nullptr,
          nullptr, 0, T_, FF_, D_, 1, 1, 12);
      gemm8_kernel<32, 64, false><<<dim3(384, 1, 1), 256, 0, stream>>>(
          Hb, FF_, 0, W2T + (size_t)i * D_ * FF_, nullptr, nullptr, FF_, 0,
          bufX, nullptr, nullptr, D_, 0, ff_b2 + (long)i * D_, nullptr, nullptr,
          bufX, D_, T_, FF_, FF_, 1, 0, 24);
    }
  } else {
    gemm5_kernel<32, 128, false><<<dim3(192, 1, 1), 256, 0, stream>>>(
        xsb, D_, 0, embed_W, nullptr, nullptr, D_, 0,
        bufT, nullptr, nullptr, D_, 0, embed_b, nullptr, nullptr,
        nullptr, 0, T_, D_, D_, 1, 0, 24);
    ln_kernel<<<T_, 256, 0, stream>>>(bufT, embed_g, embed_bt, bufX, 1e-5f, 1, 32.0f, 0);

    gemm5_kernel<128, 64, true><<<dim3(192, 1, 14), 256, 0, stream>>>(
        posT, D_, 0, Wp, nullptr, nullptr, D_, (long)szDD,
        Pall, nullptr, nullptr, D_, (long)NPOS_ * D_, nullptr, nullptr, nullptr,
        nullptr, 0, NPOS_, D_, D_, 14, 0, 12);

    for (int i = 0; i < L_; ++i) {
      ln_kernel<<<T_, 256, 0, stream>>>(bufX, ln1_g + (long)i * D_, ln1_b + (long)i * D_,
                                        XNb, 1e-12f, 0, 1.0f, 1);
      gemm5_kernel<32, 128, true><<<dim3(192, 1, 3), 256, 0, stream>>>(
          XNb, D_, 0, Wq + i * szDD, Wk + i * szDD, Wv + i * szDD, D_, 0,
          Qb, Kb, Vb, D_, 0,
          bq + (long)i * D_, bk + (long)i * D_, bv + (long)i * D_,
          nullptr, 0, T_, D_, D_, 1, 0, 24);
      flash_attn_kernel<<<dim3(T_ / 32, H_), 256, 0, stream>>>(
          Qb, Kb, Vb, Pall + (long)i * NPOS_ * D_,
          pos_u + (long)i * D_, pos_v + (long)i * D_, Ob);
      gemm5_kernel<32, 64, false><<<dim3(384, 1, 1), 256, 0, stream>>>(
          Ob, D_, 0, Wo + i * szDD, nullptr, nullptr, D_, 0,
          bufX, nullptr, nullptr, D_, 0, bo + (long)i * D_, nullptr, nullptr,
          bufX, D_, T_, D_, D_, 1, 0, 24);
      ln_kernel<<<T_, 256, 0, stream>>>(bufX, ln2_g + (long)i * D_, ln2_b + (long)i * D_,
                                        XNb, 1e-12f, 0, 1.0f, 1);
      gemm5_kernel<32, 128, true><<<dim3(768, 1, 1), 256, 0, stream>>>(
          XNb, D_, 0, ff_W1 + (size_t)i * D_ * FF_, nullptr, nullptr, FF_, 0,
          Hb, nullptr, nullptr, FF_, 0, ff_b1 + (long)i * FF_, nullptr, nullptr,
          nullptr, 0, T_, FF_, D_, 1, 1, 24);
      gemm5_kernel<32, 64, false><<<dim3(384, 1, 1), 256, 0, stream>>>(
          Hb, FF_, 0, ff_W2 + (size_t)i * D_ * FF_, nullptr, nullptr, D_, 0,
          bufX, nullptr, nullptr, D_, 0, ff_b2 + (long)i * D_, nullptr, nullptr,
          bufX, D_, T_, FF_, FF_, 1, 0, 24);
    }
  }

  ln_kernel<<<T_, 256, 0, stream>>>(bufX, after_g, after_b, out, 1e-5f, 0, 1.0f, 0);
}

// Round 16
// 2500.974 us; speedup vs baseline: 1.0204x; 1.0204x over previous
//
#include <hip/hip_runtime.h>
#include <hip/hip_bf16.h>
#include <math.h>

#define D_    1024
#define H_    16
#define HD_   64
#define L_    14
#define FF_   4096
#define T_    768
#define NPOS_ (2*T_-1)   // 1535

using s16x8 = __attribute__((ext_vector_type(8))) short;
using f32x4 = __attribute__((ext_vector_type(4))) float;

__device__ inline short f2bf(float f) {
  __hip_bfloat16 h = __float2bfloat16(f);
  return *reinterpret_cast<short*>(&h);
}
__device__ inline float bf2f(unsigned short u) {
  union { unsigned u; float f; } v; v.u = ((unsigned)u) << 16; return v.f;
}

// ---------------- reduction helpers ----------------
__device__ inline float waveRedSum(float v) {
#pragma unroll
  for (int o = 32; o > 0; o >>= 1) v += __shfl_down(v, o, 64);
  return v;
}
__device__ inline float blockRedSum(float v, float* sh) {
  int lane = threadIdx.x & 63, wid = threadIdx.x >> 6;
  v = waveRedSum(v);
  if (lane == 0) sh[wid] = v;
  __syncthreads();
  if (wid == 0) {
    float x = (lane < 4) ? sh[lane] : 0.f;
    x = waveRedSum(x);
    if (lane == 0) sh[0] = x;
  }
  __syncthreads();
  float r = sh[0];
  __syncthreads();
  return r;
}

// ---------------- LayerNorm: fp32 in, fp32-or-bf16 out (one-pass stats) ----------------
__global__ __launch_bounds__(256) void ln_kernel(
    const float* __restrict__ x, const float* __restrict__ g,
    const float* __restrict__ b, void* __restrict__ y,
    float eps, int relu, float scale, int obf)
{
  __shared__ float sh[8];
  long row = blockIdx.x;
  const float* xr = x + row * D_;
  int tid = threadIdx.x;
  float4 v = *(const float4*)&xr[tid * 4];
  float s  = v.x + v.y + v.z + v.w;
  float sq = v.x * v.x + v.y * v.y + v.z * v.z + v.w * v.w;
  float mean = blockRedSum(s, sh) * (1.f / D_);
  float esq  = blockRedSum(sq, sh) * (1.f / D_);
  float var  = esq - mean * mean;
  if (var < 0.f) var = 0.f;
  float inv = rsqrtf(var + eps);
  float4 gv = *(const float4*)&g[tid * 4];
  float4 bv = *(const float4*)&b[tid * 4];
  float o0 = (v.x - mean) * inv * gv.x + bv.x;
  float o1 = (v.y - mean) * inv * gv.y + bv.y;
  float o2 = (v.z - mean) * inv * gv.z + bv.z;
  float o3 = (v.w - mean) * inv * gv.w + bv.w;
  if (relu) {
    o0 = fmaxf(o0, 0.f); o1 = fmaxf(o1, 0.f);
    o2 = fmaxf(o2, 0.f); o3 = fmaxf(o3, 0.f);
  }
  o0 *= scale; o1 *= scale; o2 *= scale; o3 *= scale;
  if (obf) {
    short4 sv;
    sv.x = f2bf(o0); sv.y = f2bf(o1); sv.z = f2bf(o2); sv.w = f2bf(o3);
    *(short4*)&((unsigned short*)y)[row * D_ + tid * 4] = sv;
  } else {
    float4 ov; ov.x = o0; ov.y = o1; ov.z = o2; ov.w = o3;
    *(float4*)&((float*)y)[row * D_ + tid * 4] = ov;
  }
}

// ---------------- weight transpose+convert: [K][N] fp32 -> [N][K] bf16 ----------------
__global__ __launch_bounds__(256) void transpose_kernel(
    const float* __restrict__ in, unsigned short* __restrict__ out, int K, int N)
{
  __shared__ unsigned short t[32][33];
  long z = blockIdx.z;
  in  += z * (long)K * N;
  out += z * (long)K * N;
  int n0 = blockIdx.x * 32, k0 = blockIdx.y * 32;
  int tid = threadIdx.x;
  int r = tid >> 3, c4 = (tid & 7) * 4;
  float4 v = *(const float4*)&in[(long)(k0 + r) * N + n0 + c4];
  t[r][c4 + 0] = (unsigned short)f2bf(v.x);
  t[r][c4 + 1] = (unsigned short)f2bf(v.y);
  t[r][c4 + 2] = (unsigned short)f2bf(v.z);
  t[r][c4 + 3] = (unsigned short)f2bf(v.w);
  __syncthreads();
  ushort4 s;
  s.x = t[c4 + 0][r]; s.y = t[c4 + 1][r]; s.z = t[c4 + 2][r]; s.w = t[c4 + 3][r];
  *(ushort4*)&out[(long)(n0 + r) * K + k0 + c4] = s;
}

// merged transpose for the five DxD weight stacks (z = g*L + layer, g in 0..4)
__global__ __launch_bounds__(256) void transpose5_kernel(
    const float* __restrict__ W0, const float* __restrict__ W1,
    const float* __restrict__ W2, const float* __restrict__ W3,
    const float* __restrict__ W4,
    unsigned short* __restrict__ O0, unsigned short* __restrict__ O1,
    unsigned short* __restrict__ O2, unsigned short* __restrict__ O3,
    unsigned short* __restrict__ O4)
{
  __shared__ unsigned short t[32][33];
  int z = blockIdx.z;
  int g = z / L_, zi = z % L_;
  const float* in = (g == 0) ? W0 : (g == 1) ? W1 : (g == 2) ? W2 : (g == 3) ? W3 : W4;
  unsigned short* out = (g == 0) ? O0 : (g == 1) ? O1 : (g == 2) ? O2 : (g == 3) ? O3 : O4;
  in  += (long)zi * D_ * D_;
  out += (long)zi * D_ * D_;
  int n0 = blockIdx.x * 32, k0 = blockIdx.y * 32;
  int tid = threadIdx.x;
  int r = tid >> 3, c4 = (tid & 7) * 4;
  float4 v = *(const float4*)&in[(long)(k0 + r) * D_ + n0 + c4];
  t[r][c4 + 0] = (unsigned short)f2bf(v.x);
  t[r][c4 + 1] = (unsigned short)f2bf(v.y);
  t[r][c4 + 2] = (unsigned short)f2bf(v.z);
  t[r][c4 + 3] = (unsigned short)f2bf(v.w);
  __syncthreads();
  ushort4 s;
  s.x = t[c4 + 0][r]; s.y = t[c4 + 1][r]; s.z = t[c4 + 2][r]; s.w = t[c4 + 3][r];
  *(ushort4*)&out[(long)(n0 + r) * D_ + k0 + c4] = s;
}

// ---------------- gemm8: double-buffered LDS, T14 ordering (R12 exact) ----------------
template<int BM, int BN, bool CBF16>
__global__ __launch_bounds__(256) void gemm8_kernel(
    const unsigned short* __restrict__ A, int lda, long sAz,
    const unsigned short* __restrict__ B0, const unsigned short* __restrict__ B1,
    const unsigned short* __restrict__ B2, int ldb, long sBz,
    void* C0, void* C1, void* C2, int ldc, long sCz,
    const float* __restrict__ bias0, const float* __restrict__ bias1,
    const float* __restrict__ bias2,
    const float* __restrict__ resid, int ldres,
    int M, int N, int K, int zPerG, int relu, int nM)
{
  constexpr int FM = BM / 32, FN = BN / 32;
  constexpr int A_IT = BM / 32;
  constexpr int B_IT = BN / 32;

  __shared__ short As0[BM * 64];
  __shared__ short Bs0[BN * 64];
  __shared__ short As1[BM * 64];
  __shared__ short Bs1[BN * 64];

  int nb = gridDim.x, bid = blockIdx.x;
  int q = nb >> 3, r = nb & 7, xcd = bid & 7, idx = bid >> 3;
  int lbid = (xcd < r ? xcd * (q + 1) : r * (q + 1) + (xcd - r) * q) + idx;
  int mT = lbid % nM, nT = lbid / nM;
  int m0 = mT * BM, n0 = nT * BN;

  int z = blockIdx.z;
  int g = z / zPerG, zb = z - g * zPerG;
  A += (long)zb * sAz;
  const unsigned short* Bh = ((g == 0) ? B0 : ((g == 1) ? B1 : B2)) + zb * sBz;
  void* Cv = (g == 0) ? C0 : ((g == 1) ? C1 : C2);
  const float* bias = (g == 0) ? bias0 : ((g == 1) ? bias1 : bias2);
  float* Cf = (float*)Cv + zb * sCz;
  unsigned short* Ch = (unsigned short*)Cv + zb * sCz;

  int tid = threadIdx.x, lane = tid & 63, wid = tid >> 6;
  int wm0 = (wid >> 1) * (BM / 2), wn0 = (wid & 1) * (BN / 2);
  int lr = lane & 15, kl = (lane >> 4) * 8;

  f32x4 acc[FM][FN];
#pragma unroll
  for (int i = 0; i < FM; ++i)
#pragma unroll
    for (int j = 0; j < FN; ++j)
#pragma unroll
      for (int rr = 0; rr < 4; ++rr) acc[i][j][rr] = 0.f;

  s16x8 ar[A_IT], br[B_IT];

  auto loadT = [&](int k0) {
#pragma unroll
    for (int it = 0; it < A_IT; ++it) {
      int f = tid + it * 256;
      int row = f >> 3, c8 = f & 7;
      int gm = m0 + row;
      s16x8 v = {0, 0, 0, 0, 0, 0, 0, 0};
      if (gm < M) v = *(const s16x8*)(A + (long)gm * lda + k0 + c8 * 8);
      ar[it] = v;
    }
#pragma unroll
    for (int it = 0; it < B_IT; ++it) {
      int f = tid + it * 256;
      int row = f >> 3, c8 = f & 7;
      br[it] = *(const s16x8*)(Bh + (long)(n0 + row) * ldb + k0 + c8 * 8);
    }
  };
  auto writeT = [&](short* as, short* bs) {
#pragma unroll
    for (int it = 0; it < A_IT; ++it) {
      int f = tid + it * 256;
      int row = f >> 3, c8 = f & 7;
      *(s16x8*)&as[row * 64 + ((c8 ^ (row & 7)) << 3)] = ar[it];
    }
#pragma unroll
    for (int it = 0; it < B_IT; ++it) {
      int f = tid + it * 256;
      int row = f >> 3, c8 = f & 7;
      *(s16x8*)&bs[row * 64 + ((c8 ^ (row & 7)) << 3)] = br[it];
    }
  };
  auto compute = [&](const short* as, const short* bs) {
#pragma unroll
    for (int kk = 0; kk < 2; ++kk) {
      s16x8 a[FM], b[FN];
#pragma unroll
      for (int i = 0; i < FM; ++i) {
        int row = wm0 + i * 16 + lr;
        a[i] = *(const s16x8*)&as[row * 64 + ((kk * 32 + kl) ^ ((lr & 7) << 3))];
      }
#pragma unroll
      for (int j = 0; j < FN; ++j) {
        int row = wn0 + j * 16 + lr;
        b[j] = *(const s16x8*)&bs[row * 64 + ((kk * 32 + kl) ^ ((lr & 7) << 3))];
      }
#pragma unroll
      for (int i = 0; i < FM; ++i)
#pragma unroll
        for (int j = 0; j < FN; ++j)
          acc[i][j] = __builtin_amdgcn_mfma_f32_16x16x32_bf16(a[i], b[j], acc[i][j], 0, 0, 0);
    }
  };

  int nt = K / 64;                     // even
  loadT(0);
  writeT(As0, Bs0);
  __syncthreads();
  for (int t = 0; t < nt; t += 2) {
    loadT((t + 1) * 64);
    compute(As0, Bs0);
    writeT(As1, Bs1);
    __syncthreads();
    if (t + 2 < nt) loadT((t + 2) * 64);
    compute(As1, Bs1);
    if (t + 2 < nt) writeT(As0, Bs0);
    __syncthreads();
  }

#pragma unroll
  for (int i = 0; i < FM; ++i) {
#pragma unroll
    for (int j = 0; j < FN; ++j) {
      int n = n0 + wn0 + j * 16 + lr;
      float bv = bias ? bias[n] : 0.f;
#pragma unroll
      for (int rr = 0; rr < 4; ++rr) {
        int m = m0 + wm0 + i * 16 + (lane >> 4) * 4 + rr;
        if (m < M) {
          float v = acc[i][j][rr] + bv;
          if (resid) v += resid[(long)m * ldres + n];
          if (relu)  v = fmaxf(v, 0.f);
          if constexpr (CBF16) Ch[(long)m * ldc + n] = (unsigned short)f2bf(v);
          else                 Cf[(long)m * ldc + n] = v;
        }
      }
    }
  }
}

// ---------------- LDS GEMM v5 (fallback, fp32 B, single-buffered) ----------------
template<int BM, int BN, bool CBF16>
__global__ __launch_bounds__(256) void gemm5_kernel(
    const unsigned short* __restrict__ A, int lda, long sAz,
    const void* __restrict__ B0, const void* __restrict__ B1, const void* __restrict__ B2,
    int ldb, long sBz,
    void* C0, void* C1, void* C2, int ldc, long sCz,
    const float* __restrict__ bias0, const float* __restrict__ bias1,
    const float* __restrict__ bias2,
    const float* __restrict__ resid, int ldres,
    int M, int N, int K, int zPerG, int relu, int nM)
{
  constexpr int FM = BM / 32, FN = BN / 32;
  constexpr int A_IT = BM / 32;
  constexpr int NSH = (BN == 128) ? 7 : 6;

  __shared__ short As[BM * 64];
  __shared__ short Bs[BN * 64];

  int nb = gridDim.x, bid = blockIdx.x;
  int q = nb >> 3, r = nb & 7, xcd = bid & 7, idx = bid >> 3;
  int lbid = (xcd < r ? xcd * (q + 1) : r * (q + 1) + (xcd - r) * q) + idx;
  int mT = lbid % nM, nT = lbid / nM;
  int m0 = mT * BM, n0 = nT * BN;

  int z = blockIdx.z;
  int g = z / zPerG, zb = z - g * zPerG;
  A += (long)zb * sAz;
  const void* Bv = (g == 0) ? B0 : ((g == 1) ? B1 : B2);
  void* Cv       = (g == 0) ? C0 : ((g == 1) ? C1 : C2);
  const float* bias = (g == 0) ? bias0 : ((g == 1) ? bias1 : bias2);
  const float* Bf = (const float*)Bv + zb * sBz;
  float* Cf = (float*)Cv + zb * sCz;
  unsigned short* Ch = (unsigned short*)Cv + zb * sCz;

  int tid = threadIdx.x, lane = tid & 63, wid = tid >> 6;
  int wm0 = (wid >> 1) * (BM / 2), wn0 = (wid & 1) * (BN / 2);
  int lr = lane & 15, kl = (lane >> 4) * 8;

  f32x4 acc[FM][FN];
#pragma unroll
  for (int i = 0; i < FM; ++i)
#pragma unroll
    for (int j = 0; j < FN; ++j)
#pragma unroll
      for (int rr = 0; rr < 4; ++rr) acc[i][j][rr] = 0.f;

  for (int k0 = 0; k0 < K; k0 += 64) {
#pragma unroll
    for (int it = 0; it < A_IT; ++it) {
      int f = tid + it * 256;
      int row = f >> 3, c8 = f & 7;
      int gm = m0 + row;
      s16x8 v = {0, 0, 0, 0, 0, 0, 0, 0};
      if (gm < M) v = *(const s16x8*)(A + (long)gm * lda + k0 + c8 * 8);
      *(s16x8*)&As[row * 64 + ((c8 ^ (row & 7)) << 3)] = v;
    }
    constexpr int B_IT2 = BN / 16;
#pragma unroll
    for (int it = 0; it < B_IT2; ++it) {
      int p = tid + it * 256;
      int n = p & (BN - 1), kq = p >> NSH;
      int gn = n0 + n;
      const float* bp = Bf + (long)(k0 + kq * 4) * ldb + gn;
      short4 s;
      s.x = f2bf(bp[0]); s.y = f2bf(bp[ldb]);
      s.z = f2bf(bp[2 * (long)ldb]); s.w = f2bf(bp[3 * (long)ldb]);
      *(short4*)&Bs[n * 64 + ((kq << 2) ^ ((n & 7) << 3))] = s;
    }
    __syncthreads();
#pragma unroll
    for (int kk = 0; kk < 2; ++kk) {
      s16x8 a[FM], b[FN];
#pragma unroll
      for (int i = 0; i < FM; ++i) {
        int row = wm0 + i * 16 + lr;
        a[i] = *(const s16x8*)&As[row * 64 + ((kk * 32 + kl) ^ ((lr & 7) << 3))];
      }
#pragma unroll
      for (int j = 0; j < FN; ++j) {
        int row = wn0 + j * 16 + lr;
        b[j] = *(const s16x8*)&Bs[row * 64 + ((kk * 32 + kl) ^ ((lr & 7) << 3))];
      }
#pragma unroll
      for (int i = 0; i < FM; ++i)
#pragma unroll
        for (int j = 0; j < FN; ++j)
          acc[i][j] = __builtin_amdgcn_mfma_f32_16x16x32_bf16(a[i], b[j], acc[i][j], 0, 0, 0);
    }
    __syncthreads();
  }
#pragma unroll
  for (int i = 0; i < FM; ++i) {
#pragma unroll
    for (int j = 0; j < FN; ++j) {
      int n = n0 + wn0 + j * 16 + lr;
      float bv = bias ? bias[n] : 0.f;
#pragma unroll
      for (int rr = 0; rr < 4; ++rr) {
        int m = m0 + wm0 + i * 16 + (lane >> 4) * 4 + rr;
        if (m < M) {
          float v = acc[i][j][rr] + bv;
          if (resid) v += resid[(long)m * ldres + n];
          if (relu)  v = fmaxf(v, 0.f);
          if constexpr (CBF16) Ch[(long)m * ldc + n] = (unsigned short)f2bf(v);
          else                 Cf[(long)m * ldc + n] = v;
        }
      }
    }
  }
}

// ---------------- fp32 -> bf16 convert ----------------
__global__ __launch_bounds__(256) void f2bf_kernel(
    const float* __restrict__ x, unsigned short* __restrict__ y, int n4)
{
  int i = blockIdx.x * 256 + threadIdx.x;
  if (i >= n4) return;
  float4 v = *(const float4*)&x[i * 4];
  short4 s; s.x = f2bf(v.x); s.y = f2bf(v.y); s.z = f2bf(v.z); s.w = f2bf(v.w);
  *(short4*)&y[i * 4] = s;
}

// ---------------- relative positional encoding table (bf16) ----------------
__global__ __launch_bounds__(256) void pos_kernel(unsigned short* __restrict__ pos)
{
  int idx = blockIdx.x * 256 + threadIdx.x;
  if (idx >= NPOS_ * (D_ / 2)) return;
  int n = idx / (D_ / 2), i = idx % (D_ / 2);
  float r = (float)(T_ - 1 - n);
  float div = __expf((float)(2 * i) * (-logf(10000.f) / (float)D_));
  float ang = r * div;
  pos[(long)n * D_ + 2 * i]     = (unsigned short)f2bf(sinf(ang));
  pos[(long)n * D_ + 2 * i + 1] = (unsigned short)f2bf(cosf(ang));
}

// ---------------- fused flash attention with rel-shift (R12 + bank-rotated V staging) ----------------
__global__ __launch_bounds__(256) void flash_attn_kernel(
    const unsigned short* __restrict__ Q, const unsigned short* __restrict__ K,
    const unsigned short* __restrict__ V, const unsigned short* __restrict__ P,
    const float* __restrict__ posu, const float* __restrict__ posv,
    unsigned short* __restrict__ O)
{
  __shared__ short Ks[64 * 64];
  __shared__ short Vs[64 * 64];
  __shared__ short Ps[96 * 64];
  __shared__ float Grgn[32 * 99];
  __shared__ float mxls[2][32], smls[2][32];

  short* qu = (short*)Grgn;
  short* qv = qu + 32 * 64;
  float* G  = Grgn;
  short* Pf = (short*)Grgn;

  int h = blockIdx.y;
  int t0 = blockIdx.x * 32;
  int tid = threadIdx.x, lane = tid & 63, w = tid >> 6;
  int wr = w >> 1, wc = w & 1;
  int lr = lane & 15, lg = lane >> 4;
  int kl = lg * 8;
  const float* pu = posu + h * HD_;
  const float* pv = posv + h * HD_;

  {
    int row = tid >> 3, c8 = tid & 7;
    s16x8 q8 = *(const s16x8*)(Q + (long)(t0 + row) * D_ + h * HD_ + c8 * 8);
    const unsigned short* qp = (const unsigned short*)&q8;
    s16x8 su, sv;
#pragma unroll
    for (int j = 0; j < 8; ++j) {
      float qf = bf2f(qp[j]);
      su[j] = f2bf(qf + pu[c8 * 8 + j]);
      sv[j] = f2bf(qf + pv[c8 * 8 + j]);
    }
    int sw = row * 64 + ((c8 ^ (row & 7)) << 3);
    *(s16x8*)&qu[sw] = su;
    *(s16x8*)&qv[sw] = sv;
  }
  __syncthreads();
  s16x8 aqu[2], aqv[2];
#pragma unroll
  for (int kk = 0; kk < 2; ++kk) {
    int row = wr * 16 + lr;
    int col = (kk * 32 + kl) ^ ((lr & 7) << 3);
    aqu[kk] = *(const s16x8*)&qu[row * 64 + col];
    aqv[kk] = *(const s16x8*)&qv[row * 64 + col];
  }

  float m_[4], l_[4];
  f32x4 acc_o[2];
#pragma unroll
  for (int rr = 0; rr < 4; ++rr) { m_[rr] = -1e30f; l_[rr] = 0.f; }
#pragma unroll
  for (int j = 0; j < 2; ++j)
#pragma unroll
    for (int rr = 0; rr < 4; ++rr) acc_o[j][rr] = 0.f;

  for (int s0 = 0; s0 < T_; s0 += 64) {
    int base = s0 - t0 + T_ - 32;
    __syncthreads();
    // ---- stage K (16B coalesced) ----
#pragma unroll
    for (int it = 0; it < 2; ++it) {
      int f = tid + it * 256;
      int row = f >> 3, c8 = f & 7;
      s16x8 v = *(const s16x8*)(K + (long)(s0 + row) * D_ + h * HD_ + c8 * 8);
      *(s16x8*)&Ks[row * 64 + ((c8 ^ (row & 7)) << 3)] = v;
    }
    // ---- stage V^T: coalesced 16B load + bank-rotated transpose-scatter ----
    // iteration e writes element ei=(e+c8)&7 so d&7 varies across lanes -> banks spread
#pragma unroll
    for (int it = 0; it < 2; ++it) {
      int f = tid + it * 256;
      int s = f >> 3, c8 = f & 7;
      s16x8 v = *(const s16x8*)(V + (long)(s0 + s) * D_ + h * HD_ + c8 * 8);
#pragma unroll
      for (int e = 0; e < 8; ++e) {
        int ei = (e + c8) & 7;
        int d = c8 * 8 + ei;
        Vs[d * 64 + (s ^ ((d & 7) << 3))] = v[ei];
      }
    }
    // ---- stage P (16B coalesced) ----
#pragma unroll
    for (int it = 0; it < 3; ++it) {
      int f = tid + it * 256;
      int row = f >> 3, c8 = f & 7;
      int gp = base + row; if (gp > NPOS_ - 1) gp = NPOS_ - 1;
      s16x8 v = *(const s16x8*)(P + (long)gp * D_ + h * HD_ + c8 * 8);
      *(s16x8*)&Ps[row * 64 + ((c8 ^ (row & 7)) << 3)] = v;
    }
    __syncthreads();
    f32x4 a_ac[2], a_g[3];
#pragma unroll
    for (int j = 0; j < 2; ++j)
#pragma unroll
      for (int rr = 0; rr < 4; ++rr) a_ac[j][rr] = 0.f;
#pragma unroll
    for (int j = 0; j < 3; ++j)
#pragma unroll
      for (int rr = 0; rr < 4; ++rr) a_g[j][rr] = 0.f;
#pragma unroll
    for (int j = 0; j < 2; ++j)
#pragma unroll
      for (int kk = 0; kk < 2; ++kk) {
        int row = wc * 32 + j * 16 + lr;
        s16x8 b = *(const s16x8*)&Ks[row * 64 + ((kk * 32 + kl) ^ ((lr & 7) << 3))];
        a_ac[j] = __builtin_amdgcn_mfma_f32_16x16x32_bf16(aqu[kk], b, a_ac[j], 0, 0, 0);
      }
#pragma unroll
    for (int j = 0; j < 3; ++j)
#pragma unroll
      for (int kk = 0; kk < 2; ++kk) {
        int row = wc * 48 + j * 16 + lr;
        s16x8 b = *(const s16x8*)&Ps[row * 64 + ((kk * 32 + kl) ^ ((lr & 7) << 3))];
        a_g[j] = __builtin_amdgcn_mfma_f32_16x16x32_bf16(aqv[kk], b, a_g[j], 0, 0, 0);
      }
#pragma unroll
    for (int j = 0; j < 3; ++j)
#pragma unroll
      for (int rr = 0; rr < 4; ++rr) {
        int row = wr * 16 + lg * 4 + rr;
        int col = wc * 48 + j * 16 + lr;
        G[row * 99 + col] = a_g[j][rr];
      }
    __syncthreads();
    float sreg[2][4], pm[4];
#pragma unroll
    for (int rr = 0; rr < 4; ++rr) {
      int row = wr * 16 + lg * 4 + rr;
#pragma unroll
      for (int j = 0; j < 2; ++j) {
        int c = wc * 32 + j * 16 + lr;
        int gc = c - row + 31;
        sreg[j][rr] = (a_ac[j][rr] + G[row * 99 + gc]) * 0.125f;
      }
      pm[rr] = fmaxf(sreg[0][rr], sreg[1][rr]);
    }
#pragma unroll
    for (int o = 1; o < 16; o <<= 1)
#pragma unroll
      for (int rr = 0; rr < 4; ++rr) pm[rr] = fmaxf(pm[rr], __shfl_xor(pm[rr], o, 64));
    if (lr == 0) {
#pragma unroll
      for (int rr = 0; rr < 4; ++rr) mxls[wc][wr * 16 + lg * 4 + rr] = pm[rr];
    }
    __syncthreads();
    float ps[4];
#pragma unroll
    for (int rr = 0; rr < 4; ++rr) {
      int row = wr * 16 + lg * 4 + rr;
      float mnew = fmaxf(m_[rr], fmaxf(mxls[0][row], mxls[1][row]));
      float sc = __expf(m_[rr] - mnew);
      m_[rr] = mnew;
      l_[rr] *= sc;
      acc_o[0][rr] *= sc;
      acc_o[1][rr] *= sc;
      float p0 = __expf(sreg[0][rr] - mnew);
      float p1 = __expf(sreg[1][rr] - mnew);
      ps[rr] = p0 + p1;
      int c0 = wc * 32 + lr, c1 = wc * 32 + 16 + lr;
      ((unsigned short*)Pf)[row * 64 + (c0 ^ ((row & 7) << 3))] = (unsigned short)f2bf(p0);
      ((unsigned short*)Pf)[row * 64 + (c1 ^ ((row & 7) << 3))] = (unsigned short)f2bf(p1);
    }
#pragma unroll
    for (int o = 1; o < 16; o <<= 1)
#pragma unroll
      for (int rr = 0; rr < 4; ++rr) ps[rr] += __shfl_xor(ps[rr], o, 64);
    if (lr == 0) {
#pragma unroll
      for (int rr = 0; rr < 4; ++rr) smls[wc][wr * 16 + lg * 4 + rr] = ps[rr];
    }
    __syncthreads();
#pragma unroll
    for (int rr = 0; rr < 4; ++rr) {
      int row = wr * 16 + lg * 4 + rr;
      l_[rr] += smls[0][row] + smls[1][row];
    }
    s16x8 ap[2];
#pragma unroll
    for (int kk = 0; kk < 2; ++kk) {
      int row = wr * 16 + lr;
      ap[kk] = *(const s16x8*)&((unsigned short*)Pf)[row * 64 + ((kk * 32 + kl) ^ ((lr & 7) << 3))];
    }
#pragma unroll
    for (int j = 0; j < 2; ++j)
#pragma unroll
      for (int kk = 0; kk < 2; ++kk) {
        int row = wc * 32 + j * 16 + lr;
        s16x8 b = *(const s16x8*)&Vs[row * 64 + ((kk * 32 + kl) ^ ((lr & 7) << 3))];
        acc_o[j] = __builtin_amdgcn_mfma_f32_16x16x32_bf16(ap[kk], b, acc_o[j], 0, 0, 0);
      }
  }
#pragma unroll
  for (int j = 0; j < 2; ++j)
#pragma unroll
    for (int rr = 0; rr < 4; ++rr) {
      int row = t0 + wr * 16 + lg * 4 + rr;
      int col = h * HD_ + wc * 32 + j * 16 + lr;
      O[(long)row * D_ + col] = (unsigned short)f2bf(acc_o[j][rr] / l_[rr]);
    }
}

// ---------------- host side ----------------
extern "C" void kernel_launch(void* const* d_in, const int* in_sizes, int n_in,
                              void* d_out, int out_size, void* d_ws, size_t ws_size,
                              hipStream_t stream) {
  const float* xs       = (const float*)d_in[0];
  const float* embed_W  = (const float*)d_in[1];
  const float* embed_b  = (const float*)d_in[2];
  const float* embed_g  = (const float*)d_in[3];
  const float* embed_bt = (const float*)d_in[4];
  const float* Wq = (const float*)d_in[5];
  const float* bq = (const float*)d_in[6];
  const float* Wk = (const float*)d_in[7];
  const float* bk = (const float*)d_in[8];
  const float* Wv = (const float*)d_in[9];
  const float* bv = (const float*)d_in[10];
  const float* Wo = (const float*)d_in[11];
  const float* bo = (const float*)d_in[12];
  const float* Wp = (const float*)d_in[13];
  const float* pos_u = (const float*)d_in[14];
  const float* pos_v = (const float*)d_in[15];
  const float* ln1_g = (const float*)d_in[16];
  const float* ln1_b = (const float*)d_in[17];
  const float* ln2_g = (const float*)d_in[18];
  const float* ln2_b = (const float*)d_in[19];
  const float* ff_W1 = (const float*)d_in[20];
  const float* ff_b1 = (const float*)d_in[21];
  const float* ff_W2 = (const float*)d_in[22];
  const float* ff_b2 = (const float*)d_in[23];
  const float* after_g = (const float*)d_in[24];
  const float* after_b = (const float*)d_in[25];
  float* out = (float*)d_out;

  char* w = (char*)d_ws;
  auto carve = [&](size_t bytes) { char* p = w; w += (bytes + 255) & ~(size_t)255; return p; };
  float* bufX  = (float*)carve((size_t)T_ * D_ * 4);
  float* bufT  = (float*)carve((size_t)T_ * D_ * 4);
  unsigned short* xsb  = (unsigned short*)carve((size_t)T_ * D_ * 2);
  unsigned short* XNb  = (unsigned short*)carve((size_t)T_ * D_ * 2);
  unsigned short* Qb   = (unsigned short*)carve((size_t)T_ * D_ * 2);
  unsigned short* Kb   = (unsigned short*)carve((size_t)T_ * D_ * 2);
  unsigned short* Vb   = (unsigned short*)carve((size_t)T_ * D_ * 2);
  unsigned short* Ob   = (unsigned short*)carve((size_t)T_ * D_ * 2);
  unsigned short* Hb   = (unsigned short*)carve((size_t)T_ * FF_ * 2);
  unsigned short* posT = (unsigned short*)carve((size_t)(NPOS_ + 16) * D_ * 2);
  unsigned short* Pall = (unsigned short*)carve((size_t)L_ * NPOS_ * D_ * 2);
  size_t szDD = (size_t)D_ * D_;
  unsigned short* embedWt = (unsigned short*)carve(szDD * 2);
  unsigned short* WqT = (unsigned short*)carve((size_t)L_ * szDD * 2);
  unsigned short* WkT = (unsigned short*)carve((size_t)L_ * szDD * 2);
  unsigned short* WvT = (unsigned short*)carve((size_t)L_ * szDD * 2);
  unsigned short* WoT = (unsigned short*)carve((size_t)L_ * szDD * 2);
  unsigned short* WpT = (unsigned short*)carve((size_t)L_ * szDD * 2);
  unsigned short* W1T = (unsigned short*)carve((size_t)L_ * D_ * FF_ * 2);
  unsigned short* W2T = (unsigned short*)carve((size_t)L_ * D_ * FF_ * 2);
  bool fast = ((size_t)(w - (char*)d_ws) <= ws_size);

  {
    int n = NPOS_ * (D_ / 2);
    pos_kernel<<<(n + 255) / 256, 256, 0, stream>>>(posT);
  }
  f2bf_kernel<<<(T_ * D_ / 4 + 255) / 256, 256, 0, stream>>>(xs, xsb, T_ * D_ / 4);

  if (fast) {
    transpose_kernel<<<dim3(32, 32, 1),  256, 0, stream>>>(embed_W, embedWt, D_, D_);
    transpose5_kernel<<<dim3(32, 32, 5 * L_), 256, 0, stream>>>(
        Wq, Wk, Wv, Wo, Wp, WqT, WkT, WvT, WoT, WpT);
    transpose_kernel<<<dim3(128, 32, L_), 256, 0, stream>>>(ff_W1, W1T, D_, FF_);
    transpose_kernel<<<dim3(32, 128, L_), 256, 0, stream>>>(ff_W2, W2T, FF_, D_);

    gemm8_kernel<32, 128, false><<<dim3(192, 1, 1), 256, 0, stream>>>(
        xsb, D_, 0, embedWt, nullptr, nullptr, D_, 0,
        bufT, nullptr, nullptr, D_, 0, embed_b, nullptr, nullptr,
        nullptr, 0, T_, D_, D_, 1, 0, 24);
    ln_kernel<<<T_, 256, 0, stream>>>(bufT, embed_g, embed_bt, bufX, 1e-5f, 1, 32.0f, 0);

    gemm8_kernel<128, 64, true><<<dim3(192, 1, 14), 256, 0, stream>>>(
        posT, D_, 0, WpT, nullptr, nullptr, D_, (long)szDD,
        Pall, nullptr, nullptr, D_, (long)NPOS_ * D_, nullptr, nullptr, nullptr,
        nullptr, 0, NPOS_, D_, D_, 14, 0, 12);

    for (int i = 0; i < L_; ++i) {
      ln_kernel<<<T_, 256, 0, stream>>>(bufX, ln1_g + (long)i * D_, ln1_b + (long)i * D_,
                                        XNb, 1e-12f, 0, 1.0f, 1);
      gemm8_kernel<32, 128, true><<<dim3(192, 1, 3), 256, 0, stream>>>(
          XNb, D_, 0, WqT + i * szDD, WkT + i * szDD, WvT + i * szDD, D_, 0,
          Qb, Kb, Vb, D_, 0,
          bq + (long)i * D_, bk + (long)i * D_, bv + (long)i * D_,
          nullptr, 0, T_, D_, D_, 1, 0, 24);
      flash_attn_kernel<<<dim3(T_ / 32, H_), 256, 0, stream>>>(
          Qb, Kb, Vb, Pall + (long)i * NPOS_ * D_,
          pos_u + (long)i * D_, pos_v + (long)i * D_, Ob);
      gemm8_kernel<32, 64, false><<<dim3(384, 1, 1), 256, 0, stream>>>(
          Ob, D_, 0, WoT + i * szDD, nullptr, nullptr, D_, 0,
          bufX, nullptr, nullptr, D_, 0, bo + (long)i * D_, nullptr, nullptr,
          bufX, D_, T_, D_, D_, 1, 0, 24);
      ln_kernel<<<T_, 256, 0, stream>>>(bufX, ln2_g + (long)i * D_, ln2_b + (long)i * D_,
                                        XNb, 1e-12f, 0, 1.0f, 1);
      gemm8_kernel<32, 128, true><<<dim3(768, 1, 1), 256, 0, stream>>>(
          XNb, D_, 0, W1T + (size_t)i * D_ * FF_, nullptr, nullptr, D_, 0,
          Hb, nullptr, nullptr, FF_, 0, ff_b1 + (long)i * FF_, nullptr, nullptr,
          nullptr, 0, T_, FF_, D_, 1, 1, 24);
      gemm8_kernel<32, 64, false><<<dim3(384, 1, 1), 256, 0, stream>>>(
          Hb, FF_, 0, W2T + (size_t)i * D_ * FF_, nullptr, nullptr, FF_, 0,
          bufX, nullptr, nullptr, D_, 0, ff_b2 + (long)i * D_, nullptr, nullptr,
          bufX, D_, T_, FF_, FF_, 1, 0, 24);
    }
  } else {
    gemm5_kernel<32, 128, false><<<dim3(192, 1, 1), 256, 0, stream>>>(
        xsb, D_, 0, embed_W, nullptr, nullptr, D_, 0,
        bufT, nullptr, nullptr, D_, 0, embed_b, nullptr, nullptr,
        nullptr, 0, T_, D_, D_, 1, 0, 24);
    ln_kernel<<<T_, 256, 0, stream>>>(bufT, embed_g, embed_bt, bufX, 1e-5f, 1, 32.0f, 0);

    gemm5_kernel<128, 64, true><<<dim3(192, 1, 14), 256, 0, stream>>>(
        posT, D_, 0, Wp, nullptr, nullptr, D_, (long)szDD,
        Pall, nullptr, nullptr, D_, (long)NPOS_ * D_, nullptr, nullptr, nullptr,
        nullptr, 0, NPOS_, D_, D_, 14, 0, 12);

    for (int i = 0; i < L_; ++i) {
      ln_kernel<<<T_, 256, 0, stream>>>(bufX, ln1_g + (long)i * D_, ln1_b + (long)i * D_,
                                        XNb, 1e-12f, 0, 1.0f, 1);
      gemm5_kernel<32, 128, true><<<dim3(192, 1, 3), 256, 0, stream>>>(
          XNb, D_, 0, Wq + i * szDD, Wk + i * szDD, Wv + i * szDD, D_, 0,
          Qb, Kb, Vb, D_, 0,
          bq + (long)i * D_, bk + (long)i * D_, bv + (long)i * D_,
          nullptr, 0, T_, D_, D_, 1, 0, 24);
      flash_attn_kernel<<<dim3(T_ / 32, H_), 256, 0, stream>>>(
          Qb, Kb, Vb, Pall + (long)i * NPOS_ * D_,
          pos_u + (long)i * D_, pos_v + (long)i * D_, Ob);
      gemm5_kernel<32, 64, false><<<dim3(384, 1, 1), 256, 0, stream>>>(
          Ob, D_, 0, Wo + i * szDD, nullptr, nullptr, D_, 0,
          bufX, nullptr, nullptr, D_, 0, bo + (long)i * D_, nullptr, nullptr,
          bufX, D_, T_, D_, D_, 1, 0, 24);
      ln_kernel<<<T_, 256, 0, stream>>>(bufX, ln2_g + (long)i * D_, ln2_b + (long)i * D_,
                                        XNb, 1e-12f, 0, 1.0f, 1);
      gemm5_kernel<32, 128, true><<<dim3(768, 1, 1), 256, 0, stream>>>(
          XNb, D_, 0, ff_W1 + (size_t)i * D_ * FF_, nullptr, nullptr, FF_, 0,
          Hb, nullptr, nullptr, FF_, 0, ff_b1 + (long)i * FF_, nullptr, nullptr,
          nullptr, 0, T_, FF_, D_, 1, 1, 24);
      gemm5_kernel<32, 64, false><<<dim3(384, 1, 1), 256, 0, stream>>>(
          Hb, FF_, 0, ff_W2 + (size_t)i * D_ * FF_, nullptr, nullptr, D_, 0,
          bufX, nullptr, nullptr, D_, 0, ff_b2 + (long)i * D_, nullptr, nullptr,
          bufX, D_, T_, FF_, FF_, 1, 0, 24);
    }
  }

  ln_kernel<<<T_, 256, 0, stream>>>(bufX, after_g, after_b, out, 1e-5f, 0, 1.0f, 0);
}

// Round 17
// 2441.762 us; speedup vs baseline: 1.0452x; 1.0242x over previous
//
#include <hip/hip_runtime.h>
#include <hip/hip_bf16.h>
#include <math.h>

#define D_    1024
#define H_    16
#define HD_   64
#define L_    14
#define FF_   4096
#define T_    768
#define NPOS_ (2*T_-1)   // 1535

using s16x8 = __attribute__((ext_vector_type(8))) short;
using f32x4 = __attribute__((ext_vector_type(4))) float;

__device__ inline short f2bf(float f) {
  __hip_bfloat16 h = __float2bfloat16(f);
  return *reinterpret_cast<short*>(&h);
}
__device__ inline float bf2f(unsigned short u) {
  union { unsigned u; float f; } v; v.u = ((unsigned)u) << 16; return v.f;
}

// ---------------- reduction helpers ----------------
__device__ inline float waveRedSum(float v) {
#pragma unroll
  for (int o = 32; o > 0; o >>= 1) v += __shfl_down(v, o, 64);
  return v;
}
__device__ inline float blockRedSum(float v, float* sh) {
  int lane = threadIdx.x & 63, wid = threadIdx.x >> 6;
  v = waveRedSum(v);
  if (lane == 0) sh[wid] = v;
  __syncthreads();
  if (wid == 0) {
    float x = (lane < 4) ? sh[lane] : 0.f;
    x = waveRedSum(x);
    if (lane == 0) sh[0] = x;
  }
  __syncthreads();
  float r = sh[0];
  __syncthreads();
  return r;
}

// ---------------- LayerNorm: fp32 in, fp32-or-bf16 out (one-pass stats) ----------------
__global__ __launch_bounds__(256) void ln_kernel(
    const float* __restrict__ x, const float* __restrict__ g,
    const float* __restrict__ b, void* __restrict__ y,
    float eps, int relu, float scale, int obf)
{
  __shared__ float sh[8];
  long row = blockIdx.x;
  const float* xr = x + row * D_;
  int tid = threadIdx.x;
  float4 v = *(const float4*)&xr[tid * 4];
  float s  = v.x + v.y + v.z + v.w;
  float sq = v.x * v.x + v.y * v.y + v.z * v.z + v.w * v.w;
  float mean = blockRedSum(s, sh) * (1.f / D_);
  float esq  = blockRedSum(sq, sh) * (1.f / D_);
  float var  = esq - mean * mean;
  if (var < 0.f) var = 0.f;
  float inv = rsqrtf(var + eps);
  float4 gv = *(const float4*)&g[tid * 4];
  float4 bv = *(const float4*)&b[tid * 4];
  float o0 = (v.x - mean) * inv * gv.x + bv.x;
  float o1 = (v.y - mean) * inv * gv.y + bv.y;
  float o2 = (v.z - mean) * inv * gv.z + bv.z;
  float o3 = (v.w - mean) * inv * gv.w + bv.w;
  if (relu) {
    o0 = fmaxf(o0, 0.f); o1 = fmaxf(o1, 0.f);
    o2 = fmaxf(o2, 0.f); o3 = fmaxf(o3, 0.f);
  }
  o0 *= scale; o1 *= scale; o2 *= scale; o3 *= scale;
  if (obf) {
    short4 sv;
    sv.x = f2bf(o0); sv.y = f2bf(o1); sv.z = f2bf(o2); sv.w = f2bf(o3);
    *(short4*)&((unsigned short*)y)[row * D_ + tid * 4] = sv;
  } else {
    float4 ov; ov.x = o0; ov.y = o1; ov.z = o2; ov.w = o3;
    *(float4*)&((float*)y)[row * D_ + tid * 4] = ov;
  }
}

// ---------------- weight transpose+convert: [K][N] fp32 -> [N][K] bf16 ----------------
__global__ __launch_bounds__(256) void transpose_kernel(
    const float* __restrict__ in, unsigned short* __restrict__ out, int K, int N)
{
  __shared__ unsigned short t[32][33];
  long z = blockIdx.z;
  in  += z * (long)K * N;
  out += z * (long)K * N;
  int n0 = blockIdx.x * 32, k0 = blockIdx.y * 32;
  int tid = threadIdx.x;
  int r = tid >> 3, c4 = (tid & 7) * 4;
  float4 v = *(const float4*)&in[(long)(k0 + r) * N + n0 + c4];
  t[r][c4 + 0] = (unsigned short)f2bf(v.x);
  t[r][c4 + 1] = (unsigned short)f2bf(v.y);
  t[r][c4 + 2] = (unsigned short)f2bf(v.z);
  t[r][c4 + 3] = (unsigned short)f2bf(v.w);
  __syncthreads();
  ushort4 s;
  s.x = t[c4 + 0][r]; s.y = t[c4 + 1][r]; s.z = t[c4 + 2][r]; s.w = t[c4 + 3][r];
  *(ushort4*)&out[(long)(n0 + r) * K + k0 + c4] = s;
}

// merged transpose for the five DxD weight stacks (z = g*L + layer, g in 0..4)
__global__ __launch_bounds__(256) void transpose5_kernel(
    const float* __restrict__ W0, const float* __restrict__ W1,
    const float* __restrict__ W2, const float* __restrict__ W3,
    const float* __restrict__ W4,
    unsigned short* __restrict__ O0, unsigned short* __restrict__ O1,
    unsigned short* __restrict__ O2, unsigned short* __restrict__ O3,
    unsigned short* __restrict__ O4)
{
  __shared__ unsigned short t[32][33];
  int z = blockIdx.z;
  int g = z / L_, zi = z % L_;
  const float* in = (g == 0) ? W0 : (g == 1) ? W1 : (g == 2) ? W2 : (g == 3) ? W3 : W4;
  unsigned short* out = (g == 0) ? O0 : (g == 1) ? O1 : (g == 2) ? O2 : (g == 3) ? O3 : O4;
  in  += (long)zi * D_ * D_;
  out += (long)zi * D_ * D_;
  int n0 = blockIdx.x * 32, k0 = blockIdx.y * 32;
  int tid = threadIdx.x;
  int r = tid >> 3, c4 = (tid & 7) * 4;
  float4 v = *(const float4*)&in[(long)(k0 + r) * D_ + n0 + c4];
  t[r][c4 + 0] = (unsigned short)f2bf(v.x);
  t[r][c4 + 1] = (unsigned short)f2bf(v.y);
  t[r][c4 + 2] = (unsigned short)f2bf(v.z);
  t[r][c4 + 3] = (unsigned short)f2bf(v.w);
  __syncthreads();
  ushort4 s;
  s.x = t[c4 + 0][r]; s.y = t[c4 + 1][r]; s.z = t[c4 + 2][r]; s.w = t[c4 + 3][r];
  *(ushort4*)&out[(long)(n0 + r) * D_ + k0 + c4] = s;
}

// ---------------- gemm8: double-buffered LDS, T14 ordering (R12 exact) ----------------
template<int BM, int BN, bool CBF16>
__global__ __launch_bounds__(256) void gemm8_kernel(
    const unsigned short* __restrict__ A, int lda, long sAz,
    const unsigned short* __restrict__ B0, const unsigned short* __restrict__ B1,
    const unsigned short* __restrict__ B2, int ldb, long sBz,
    void* C0, void* C1, void* C2, int ldc, long sCz,
    const float* __restrict__ bias0, const float* __restrict__ bias1,
    const float* __restrict__ bias2,
    const float* __restrict__ resid, int ldres,
    int M, int N, int K, int zPerG, int relu, int nM)
{
  constexpr int FM = BM / 32, FN = BN / 32;
  constexpr int A_IT = BM / 32;
  constexpr int B_IT = BN / 32;

  __shared__ short As0[BM * 64];
  __shared__ short Bs0[BN * 64];
  __shared__ short As1[BM * 64];
  __shared__ short Bs1[BN * 64];

  int nb = gridDim.x, bid = blockIdx.x;
  int q = nb >> 3, r = nb & 7, xcd = bid & 7, idx = bid >> 3;
  int lbid = (xcd < r ? xcd * (q + 1) : r * (q + 1) + (xcd - r) * q) + idx;
  int mT = lbid % nM, nT = lbid / nM;
  int m0 = mT * BM, n0 = nT * BN;

  int z = blockIdx.z;
  int g = z / zPerG, zb = z - g * zPerG;
  A += (long)zb * sAz;
  const unsigned short* Bh = ((g == 0) ? B0 : ((g == 1) ? B1 : B2)) + zb * sBz;
  void* Cv = (g == 0) ? C0 : ((g == 1) ? C1 : C2);
  const float* bias = (g == 0) ? bias0 : ((g == 1) ? bias1 : bias2);
  float* Cf = (float*)Cv + zb * sCz;
  unsigned short* Ch = (unsigned short*)Cv + zb * sCz;

  int tid = threadIdx.x, lane = tid & 63, wid = tid >> 6;
  int wm0 = (wid >> 1) * (BM / 2), wn0 = (wid & 1) * (BN / 2);
  int lr = lane & 15, kl = (lane >> 4) * 8;

  f32x4 acc[FM][FN];
#pragma unroll
  for (int i = 0; i < FM; ++i)
#pragma unroll
    for (int j = 0; j < FN; ++j)
#pragma unroll
      for (int rr = 0; rr < 4; ++rr) acc[i][j][rr] = 0.f;

  s16x8 ar[A_IT], br[B_IT];

  auto loadT = [&](int k0) {
#pragma unroll
    for (int it = 0; it < A_IT; ++it) {
      int f = tid + it * 256;
      int row = f >> 3, c8 = f & 7;
      int gm = m0 + row;
      s16x8 v = {0, 0, 0, 0, 0, 0, 0, 0};
      if (gm < M) v = *(const s16x8*)(A + (long)gm * lda + k0 + c8 * 8);
      ar[it] = v;
    }
#pragma unroll
    for (int it = 0; it < B_IT; ++it) {
      int f = tid + it * 256;
      int row = f >> 3, c8 = f & 7;
      br[it] = *(const s16x8*)(Bh + (long)(n0 + row) * ldb + k0 + c8 * 8);
    }
  };
  auto writeT = [&](short* as, short* bs) {
#pragma unroll
    for (int it = 0; it < A_IT; ++it) {
      int f = tid + it * 256;
      int row = f >> 3, c8 = f & 7;
      *(s16x8*)&as[row * 64 + ((c8 ^ (row & 7)) << 3)] = ar[it];
    }
#pragma unroll
    for (int it = 0; it < B_IT; ++it) {
      int f = tid + it * 256;
      int row = f >> 3, c8 = f & 7;
      *(s16x8*)&bs[row * 64 + ((c8 ^ (row & 7)) << 3)] = br[it];
    }
  };
  auto compute = [&](const short* as, const short* bs) {
#pragma unroll
    for (int kk = 0; kk < 2; ++kk) {
      s16x8 a[FM], b[FN];
#pragma unroll
      for (int i = 0; i < FM; ++i) {
        int row = wm0 + i * 16 + lr;
        a[i] = *(const s16x8*)&as[row * 64 + ((kk * 32 + kl) ^ ((lr & 7) << 3))];
      }
#pragma unroll
      for (int j = 0; j < FN; ++j) {
        int row = wn0 + j * 16 + lr;
        b[j] = *(const s16x8*)&bs[row * 64 + ((kk * 32 + kl) ^ ((lr & 7) << 3))];
      }
#pragma unroll
      for (int i = 0; i < FM; ++i)
#pragma unroll
        for (int j = 0; j < FN; ++j)
          acc[i][j] = __builtin_amdgcn_mfma_f32_16x16x32_bf16(a[i], b[j], acc[i][j], 0, 0, 0);
    }
  };

  int nt = K / 64;                     // even
  loadT(0);
  writeT(As0, Bs0);
  __syncthreads();
  for (int t = 0; t < nt; t += 2) {
    loadT((t + 1) * 64);
    compute(As0, Bs0);
    writeT(As1, Bs1);
    __syncthreads();
    if (t + 2 < nt) loadT((t + 2) * 64);
    compute(As1, Bs1);
    if (t + 2 < nt) writeT(As0, Bs0);
    __syncthreads();
  }

#pragma unroll
  for (int i = 0; i < FM; ++i) {
#pragma unroll
    for (int j = 0; j < FN; ++j) {
      int n = n0 + wn0 + j * 16 + lr;
      float bv = bias ? bias[n] : 0.f;
#pragma unroll
      for (int rr = 0; rr < 4; ++rr) {
        int m = m0 + wm0 + i * 16 + (lane >> 4) * 4 + rr;
        if (m < M) {
          float v = acc[i][j][rr] + bv;
          if (resid) v += resid[(long)m * ldres + n];
          if (relu)  v = fmaxf(v, 0.f);
          if constexpr (CBF16) Ch[(long)m * ldc + n] = (unsigned short)f2bf(v);
          else                 Cf[(long)m * ldc + n] = v;
        }
      }
    }
  }
}

// ---------------- LDS GEMM v5 (fallback, fp32 B, single-buffered) ----------------
template<int BM, int BN, bool CBF16>
__global__ __launch_bounds__(256) void gemm5_kernel(
    const unsigned short* __restrict__ A, int lda, long sAz,
    const void* __restrict__ B0, const void* __restrict__ B1, const void* __restrict__ B2,
    int ldb, long sBz,
    void* C0, void* C1, void* C2, int ldc, long sCz,
    const float* __restrict__ bias0, const float* __restrict__ bias1,
    const float* __restrict__ bias2,
    const float* __restrict__ resid, int ldres,
    int M, int N, int K, int zPerG, int relu, int nM)
{
  constexpr int FM = BM / 32, FN = BN / 32;
  constexpr int A_IT = BM / 32;
  constexpr int NSH = (BN == 128) ? 7 : 6;

  __shared__ short As[BM * 64];
  __shared__ short Bs[BN * 64];

  int nb = gridDim.x, bid = blockIdx.x;
  int q = nb >> 3, r = nb & 7, xcd = bid & 7, idx = bid >> 3;
  int lbid = (xcd < r ? xcd * (q + 1) : r * (q + 1) + (xcd - r) * q) + idx;
  int mT = lbid % nM, nT = lbid / nM;
  int m0 = mT * BM, n0 = nT * BN;

  int z = blockIdx.z;
  int g = z / zPerG, zb = z - g * zPerG;
  A += (long)zb * sAz;
  const void* Bv = (g == 0) ? B0 : ((g == 1) ? B1 : B2);
  void* Cv       = (g == 0) ? C0 : ((g == 1) ? C1 : C2);
  const float* bias = (g == 0) ? bias0 : ((g == 1) ? bias1 : bias2);
  const float* Bf = (const float*)Bv + zb * sBz;
  float* Cf = (float*)Cv + zb * sCz;
  unsigned short* Ch = (unsigned short*)Cv + zb * sCz;

  int tid = threadIdx.x, lane = tid & 63, wid = tid >> 6;
  int wm0 = (wid >> 1) * (BM / 2), wn0 = (wid & 1) * (BN / 2);
  int lr = lane & 15, kl = (lane >> 4) * 8;

  f32x4 acc[FM][FN];
#pragma unroll
  for (int i = 0; i < FM; ++i)
#pragma unroll
    for (int j = 0; j < FN; ++j)
#pragma unroll
      for (int rr = 0; rr < 4; ++rr) acc[i][j][rr] = 0.f;

  for (int k0 = 0; k0 < K; k0 += 64) {
#pragma unroll
    for (int it = 0; it < A_IT; ++it) {
      int f = tid + it * 256;
      int row = f >> 3, c8 = f & 7;
      int gm = m0 + row;
      s16x8 v = {0, 0, 0, 0, 0, 0, 0, 0};
      if (gm < M) v = *(const s16x8*)(A + (long)gm * lda + k0 + c8 * 8);
      *(s16x8*)&As[row * 64 + ((c8 ^ (row & 7)) << 3)] = v;
    }
    constexpr int B_IT2 = BN / 16;
#pragma unroll
    for (int it = 0; it < B_IT2; ++it) {
      int p = tid + it * 256;
      int n = p & (BN - 1), kq = p >> NSH;
      int gn = n0 + n;
      const float* bp = Bf + (long)(k0 + kq * 4) * ldb + gn;
      short4 s;
      s.x = f2bf(bp[0]); s.y = f2bf(bp[ldb]);
      s.z = f2bf(bp[2 * (long)ldb]); s.w = f2bf(bp[3 * (long)ldb]);
      *(short4*)&Bs[n * 64 + ((kq << 2) ^ ((n & 7) << 3))] = s;
    }
    __syncthreads();
#pragma unroll
    for (int kk = 0; kk < 2; ++kk) {
      s16x8 a[FM], b[FN];
#pragma unroll
      for (int i = 0; i < FM; ++i) {
        int row = wm0 + i * 16 + lr;
        a[i] = *(const s16x8*)&As[row * 64 + ((kk * 32 + kl) ^ ((lr & 7) << 3))];
      }
#pragma unroll
      for (int j = 0; j < FN; ++j) {
        int row = wn0 + j * 16 + lr;
        b[j] = *(const s16x8*)&Bs[row * 64 + ((kk * 32 + kl) ^ ((lr & 7) << 3))];
      }
#pragma unroll
      for (int i = 0; i < FM; ++i)
#pragma unroll
        for (int j = 0; j < FN; ++j)
          acc[i][j] = __builtin_amdgcn_mfma_f32_16x16x32_bf16(a[i], b[j], acc[i][j], 0, 0, 0);
    }
    __syncthreads();
  }
#pragma unroll
  for (int i = 0; i < FM; ++i) {
#pragma unroll
    for (int j = 0; j < FN; ++j) {
      int n = n0 + wn0 + j * 16 + lr;
      float bv = bias ? bias[n] : 0.f;
#pragma unroll
      for (int rr = 0; rr < 4; ++rr) {
        int m = m0 + wm0 + i * 16 + (lane >> 4) * 4 + rr;
        if (m < M) {
          float v = acc[i][j][rr] + bv;
          if (resid) v += resid[(long)m * ldres + n];
          if (relu)  v = fmaxf(v, 0.f);
          if constexpr (CBF16) Ch[(long)m * ldc + n] = (unsigned short)f2bf(v);
          else                 Cf[(long)m * ldc + n] = v;
        }
      }
    }
  }
}

// ---------------- fp32 -> bf16 convert ----------------
__global__ __launch_bounds__(256) void f2bf_kernel(
    const float* __restrict__ x, unsigned short* __restrict__ y, int n4)
{
  int i = blockIdx.x * 256 + threadIdx.x;
  if (i >= n4) return;
  float4 v = *(const float4*)&x[i * 4];
  short4 s; s.x = f2bf(v.x); s.y = f2bf(v.y); s.z = f2bf(v.z); s.w = f2bf(v.w);
  *(short4*)&y[i * 4] = s;
}

// ---------------- relative positional encoding table (bf16) ----------------
__global__ __launch_bounds__(256) void pos_kernel(unsigned short* __restrict__ pos)
{
  int idx = blockIdx.x * 256 + threadIdx.x;
  if (idx >= NPOS_ * (D_ / 2)) return;
  int n = idx / (D_ / 2), i = idx % (D_ / 2);
  float r = (float)(T_ - 1 - n);
  float div = __expf((float)(2 * i) * (-logf(10000.f) / (float)D_));
  float ang = r * div;
  pos[(long)n * D_ + 2 * i]     = (unsigned short)f2bf(sinf(ang));
  pos[(long)n * D_ + 2 * i + 1] = (unsigned short)f2bf(cosf(ang));
}

// ---------------- fused flash attention with rel-shift (R12 exact) ----------------
__global__ __launch_bounds__(256) void flash_attn_kernel(
    const unsigned short* __restrict__ Q, const unsigned short* __restrict__ K,
    const unsigned short* __restrict__ V, const unsigned short* __restrict__ P,
    const float* __restrict__ posu, const float* __restrict__ posv,
    unsigned short* __restrict__ O)
{
  __shared__ short Ks[64 * 64];
  __shared__ short Vs[64 * 64];
  __shared__ short Ps[96 * 64];
  __shared__ float Grgn[32 * 99];
  __shared__ float mxls[2][32], smls[2][32];

  short* qu = (short*)Grgn;
  short* qv = qu + 32 * 64;
  float* G  = Grgn;
  short* Pf = (short*)Grgn;

  int h = blockIdx.y;
  int t0 = blockIdx.x * 32;
  int tid = threadIdx.x, lane = tid & 63, w = tid >> 6;
  int wr = w >> 1, wc = w & 1;
  int lr = lane & 15, lg = lane >> 4;
  int kl = lg * 8;
  const float* pu = posu + h * HD_;
  const float* pv = posv + h * HD_;

  {
    int row = tid >> 3, c8 = tid & 7;
    s16x8 q8 = *(const s16x8*)(Q + (long)(t0 + row) * D_ + h * HD_ + c8 * 8);
    const unsigned short* qp = (const unsigned short*)&q8;
    s16x8 su, sv;
#pragma unroll
    for (int j = 0; j < 8; ++j) {
      float qf = bf2f(qp[j]);
      su[j] = f2bf(qf + pu[c8 * 8 + j]);
      sv[j] = f2bf(qf + pv[c8 * 8 + j]);
    }
    int sw = row * 64 + ((c8 ^ (row & 7)) << 3);
    *(s16x8*)&qu[sw] = su;
    *(s16x8*)&qv[sw] = sv;
  }
  __syncthreads();
  s16x8 aqu[2], aqv[2];
#pragma unroll
  for (int kk = 0; kk < 2; ++kk) {
    int row = wr * 16 + lr;
    int col = (kk * 32 + kl) ^ ((lr & 7) << 3);
    aqu[kk] = *(const s16x8*)&qu[row * 64 + col];
    aqv[kk] = *(const s16x8*)&qv[row * 64 + col];
  }

  float m_[4], l_[4];
  f32x4 acc_o[2];
#pragma unroll
  for (int rr = 0; rr < 4; ++rr) { m_[rr] = -1e30f; l_[rr] = 0.f; }
#pragma unroll
  for (int j = 0; j < 2; ++j)
#pragma unroll
    for (int rr = 0; rr < 4; ++rr) acc_o[j][rr] = 0.f;

  for (int s0 = 0; s0 < T_; s0 += 64) {
    int base = s0 - t0 + T_ - 32;
    __syncthreads();
#pragma unroll
    for (int it = 0; it < 2; ++it) {
      int f = tid + it * 256;
      int row = f >> 3, c8 = f & 7;
      s16x8 v = *(const s16x8*)(K + (long)(s0 + row) * D_ + h * HD_ + c8 * 8);
      *(s16x8*)&Ks[row * 64 + ((c8 ^ (row & 7)) << 3)] = v;
    }
#pragma unroll
    for (int it = 0; it < 4; ++it) {
      int d = tid & 63, sq = tid >> 6;
      int s = it * 16 + sq * 4;
      const unsigned short* vp = V + (long)(s0 + s) * D_ + h * HD_ + d;
      short4 sv4;
      sv4.x = (short)vp[0];
      sv4.y = (short)vp[D_];
      sv4.z = (short)vp[2 * D_];
      sv4.w = (short)vp[3 * D_];
      *(short4*)&Vs[d * 64 + (s ^ ((d & 7) << 3))] = sv4;
    }
#pragma unroll
    for (int it = 0; it < 3; ++it) {
      int f = tid + it * 256;
      int row = f >> 3, c8 = f & 7;
      int gp = base + row; if (gp > NPOS_ - 1) gp = NPOS_ - 1;
      s16x8 v = *(const s16x8*)(P + (long)gp * D_ + h * HD_ + c8 * 8);
      *(s16x8*)&Ps[row * 64 + ((c8 ^ (row & 7)) << 3)] = v;
    }
    __syncthreads();
    f32x4 a_ac[2], a_g[3];
#pragma unroll
    for (int j = 0; j < 2; ++j)
#pragma unroll
      for (int rr = 0; rr < 4; ++rr) a_ac[j][rr] = 0.f;
#pragma unroll
    for (int j = 0; j < 3; ++j)
#pragma unroll
      for (int rr = 0; rr < 4; ++rr) a_g[j][rr] = 0.f;
#pragma unroll
    for (int j = 0; j < 2; ++j)
#pragma unroll
      for (int kk = 0; kk < 2; ++kk) {
        int row = wc * 32 + j * 16 + lr;
        s16x8 b = *(const s16x8*)&Ks[row * 64 + ((kk * 32 + kl) ^ ((lr & 7) << 3))];
        a_ac[j] = __builtin_amdgcn_mfma_f32_16x16x32_bf16(aqu[kk], b, a_ac[j], 0, 0, 0);
      }
#pragma unroll
    for (int j = 0; j < 3; ++j)
#pragma unroll
      for (int kk = 0; kk < 2; ++kk) {
        int row = wc * 48 + j * 16 + lr;
        s16x8 b = *(const s16x8*)&Ps[row * 64 + ((kk * 32 + kl) ^ ((lr & 7) << 3))];
        a_g[j] = __builtin_amdgcn_mfma_f32_16x16x32_bf16(aqv[kk], b, a_g[j], 0, 0, 0);
      }
#pragma unroll
    for (int j = 0; j < 3; ++j)
#pragma unroll
      for (int rr = 0; rr < 4; ++rr) {
        int row = wr * 16 + lg * 4 + rr;
        int col = wc * 48 + j * 16 + lr;
        G[row * 99 + col] = a_g[j][rr];
      }
    __syncthreads();
    float sreg[2][4], pm[4];
#pragma unroll
    for (int rr = 0; rr < 4; ++rr) {
      int row = wr * 16 + lg * 4 + rr;
#pragma unroll
      for (int j = 0; j < 2; ++j) {
        int c = wc * 32 + j * 16 + lr;
        int gc = c - row + 31;
        sreg[j][rr] = (a_ac[j][rr] + G[row * 99 + gc]) * 0.125f;
      }
      pm[rr] = fmaxf(sreg[0][rr], sreg[1][rr]);
    }
#pragma unroll
    for (int o = 1; o < 16; o <<= 1)
#pragma unroll
      for (int rr = 0; rr < 4; ++rr) pm[rr] = fmaxf(pm[rr], __shfl_xor(pm[rr], o, 64));
    if (lr == 0) {
#pragma unroll
      for (int rr = 0; rr < 4; ++rr) mxls[wc][wr * 16 + lg * 4 + rr] = pm[rr];
    }
    __syncthreads();
    float ps[4];
#pragma unroll
    for (int rr = 0; rr < 4; ++rr) {
      int row = wr * 16 + lg * 4 + rr;
      float mnew = fmaxf(m_[rr], fmaxf(mxls[0][row], mxls[1][row]));
      float sc = __expf(m_[rr] - mnew);
      m_[rr] = mnew;
      l_[rr] *= sc;
      acc_o[0][rr] *= sc;
      acc_o[1][rr] *= sc;
      float p0 = __expf(sreg[0][rr] - mnew);
      float p1 = __expf(sreg[1][rr] - mnew);
      ps[rr] = p0 + p1;
      int c0 = wc * 32 + lr, c1 = wc * 32 + 16 + lr;
      ((unsigned short*)Pf)[row * 64 + (c0 ^ ((row & 7) << 3))] = (unsigned short)f2bf(p0);
      ((unsigned short*)Pf)[row * 64 + (c1 ^ ((row & 7) << 3))] = (unsigned short)f2bf(p1);
    }
#pragma unroll
    for (int o = 1; o < 16; o <<= 1)
#pragma unroll
      for (int rr = 0; rr < 4; ++rr) ps[rr] += __shfl_xor(ps[rr], o, 64);
    if (lr == 0) {
#pragma unroll
      for (int rr = 0; rr < 4; ++rr) smls[wc][wr * 16 + lg * 4 + rr] = ps[rr];
    }
    __syncthreads();
#pragma unroll
    for (int rr = 0; rr < 4; ++rr) {
      int row = wr * 16 + lg * 4 + rr;
      l_[rr] += smls[0][row] + smls[1][row];
    }
    s16x8 ap[2];
#pragma unroll
    for (int kk = 0; kk < 2; ++kk) {
      int row = wr * 16 + lr;
      ap[kk] = *(const s16x8*)&((unsigned short*)Pf)[row * 64 + ((kk * 32 + kl) ^ ((lr & 7) << 3))];
    }
#pragma unroll
    for (int j = 0; j < 2; ++j)
#pragma unroll
      for (int kk = 0; kk < 2; ++kk) {
        int row = wc * 32 + j * 16 + lr;
        s16x8 b = *(const s16x8*)&Vs[row * 64 + ((kk * 32 + kl) ^ ((lr & 7) << 3))];
        acc_o[j] = __builtin_amdgcn_mfma_f32_16x16x32_bf16(ap[kk], b, acc_o[j], 0, 0, 0);
      }
  }
#pragma unroll
  for (int j = 0; j < 2; ++j)
#pragma unroll
    for (int rr = 0; rr < 4; ++rr) {
      int row = t0 + wr * 16 + lg * 4 + rr;
      int col = h * HD_ + wc * 32 + j * 16 + lr;
      O[(long)row * D_ + col] = (unsigned short)f2bf(acc_o[j][rr] / l_[rr]);
    }
}

// ---------------- host side ----------------
extern "C" void kernel_launch(void* const* d_in, const int* in_sizes, int n_in,
                              void* d_out, int out_size, void* d_ws, size_t ws_size,
                              hipStream_t stream) {
  const float* xs       = (const float*)d_in[0];
  const float* embed_W  = (const float*)d_in[1];
  const float* embed_b  = (const float*)d_in[2];
  const float* embed_g  = (const float*)d_in[3];
  const float* embed_bt = (const float*)d_in[4];
  const float* Wq = (const float*)d_in[5];
  const float* bq = (const float*)d_in[6];
  const float* Wk = (const float*)d_in[7];
  const float* bk = (const float*)d_in[8];
  const float* Wv = (const float*)d_in[9];
  const float* bv = (const float*)d_in[10];
  const float* Wo = (const float*)d_in[11];
  const float* bo = (const float*)d_in[12];
  const float* Wp = (const float*)d_in[13];
  const float* pos_u = (const float*)d_in[14];
  const float* pos_v = (const float*)d_in[15];
  const float* ln1_g = (const float*)d_in[16];
  const float* ln1_b = (const float*)d_in[17];
  const float* ln2_g = (const float*)d_in[18];
  const float* ln2_b = (const float*)d_in[19];
  const float* ff_W1 = (const float*)d_in[20];
  const float* ff_b1 = (const float*)d_in[21];
  const float* ff_W2 = (const float*)d_in[22];
  const float* ff_b2 = (const float*)d_in[23];
  const float* after_g = (const float*)d_in[24];
  const float* after_b = (const float*)d_in[25];
  float* out = (float*)d_out;

  char* w = (char*)d_ws;
  auto carve = [&](size_t bytes) { char* p = w; w += (bytes + 255) & ~(size_t)255; return p; };
  float* bufX  = (float*)carve((size_t)T_ * D_ * 4);
  float* bufT  = (float*)carve((size_t)T_ * D_ * 4);
  unsigned short* xsb  = (unsigned short*)carve((size_t)T_ * D_ * 2);
  unsigned short* XNb  = (unsigned short*)carve((size_t)T_ * D_ * 2);
  unsigned short* Qb   = (unsigned short*)carve((size_t)T_ * D_ * 2);
  unsigned short* Kb   = (unsigned short*)carve((size_t)T_ * D_ * 2);
  unsigned short* Vb   = (unsigned short*)carve((size_t)T_ * D_ * 2);
  unsigned short* Ob   = (unsigned short*)carve((size_t)T_ * D_ * 2);
  unsigned short* Hb   = (unsigned short*)carve((size_t)T_ * FF_ * 2);
  unsigned short* posT = (unsigned short*)carve((size_t)(NPOS_ + 16) * D_ * 2);
  unsigned short* Pall = (unsigned short*)carve((size_t)L_ * NPOS_ * D_ * 2);
  size_t szDD = (size_t)D_ * D_;
  unsigned short* embedWt = (unsigned short*)carve(szDD * 2);
  unsigned short* WqT = (unsigned short*)carve((size_t)L_ * szDD * 2);
  unsigned short* WkT = (unsigned short*)carve((size_t)L_ * szDD * 2);
  unsigned short* WvT = (unsigned short*)carve((size_t)L_ * szDD * 2);
  unsigned short* WoT = (unsigned short*)carve((size_t)L_ * szDD * 2);
  unsigned short* WpT = (unsigned short*)carve((size_t)L_ * szDD * 2);
  unsigned short* W1T = (unsigned short*)carve((size_t)L_ * D_ * FF_ * 2);
  unsigned short* W2T = (unsigned short*)carve((size_t)L_ * D_ * FF_ * 2);
  bool fast = ((size_t)(w - (char*)d_ws) <= ws_size);

  {
    int n = NPOS_ * (D_ / 2);
    pos_kernel<<<(n + 255) / 256, 256, 0, stream>>>(posT);
  }
  f2bf_kernel<<<(T_ * D_ / 4 + 255) / 256, 256, 0, stream>>>(xs, xsb, T_ * D_ / 4);

  if (fast) {
    transpose_kernel<<<dim3(32, 32, 1),  256, 0, stream>>>(embed_W, embedWt, D_, D_);
    transpose5_kernel<<<dim3(32, 32, 5 * L_), 256, 0, stream>>>(
        Wq, Wk, Wv, Wo, Wp, WqT, WkT, WvT, WoT, WpT);
    transpose_kernel<<<dim3(128, 32, L_), 256, 0, stream>>>(ff_W1, W1T, D_, FF_);
    transpose_kernel<<<dim3(32, 128, L_), 256, 0, stream>>>(ff_W2, W2T, FF_, D_);

    gemm8_kernel<32, 128, false><<<dim3(192, 1, 1), 256, 0, stream>>>(
        xsb, D_, 0, embedWt, nullptr, nullptr, D_, 0,
        bufT, nullptr, nullptr, D_, 0, embed_b, nullptr, nullptr,
        nullptr, 0, T_, D_, D_, 1, 0, 24);
    ln_kernel<<<T_, 256, 0, stream>>>(bufT, embed_g, embed_bt, bufX, 1e-5f, 1, 32.0f, 0);

    gemm8_kernel<128, 64, true><<<dim3(192, 1, 14), 256, 0, stream>>>(
        posT, D_, 0, WpT, nullptr, nullptr, D_, (long)szDD,
        Pall, nullptr, nullptr, D_, (long)NPOS_ * D_, nullptr, nullptr, nullptr,
        nullptr, 0, NPOS_, D_, D_, 14, 0, 12);

    for (int i = 0; i < L_; ++i) {
      ln_kernel<<<T_, 256, 0, stream>>>(bufX, ln1_g + (long)i * D_, ln1_b + (long)i * D_,
                                        XNb, 1e-12f, 0, 1.0f, 1);
      gemm8_kernel<32, 128, true><<<dim3(192, 1, 3), 256, 0, stream>>>(
          XNb, D_, 0, WqT + i * szDD, WkT + i * szDD, WvT + i * szDD, D_, 0,
          Qb, Kb, Vb, D_, 0,
          bq + (long)i * D_, bk + (long)i * D_, bv + (long)i * D_,
          nullptr, 0, T_, D_, D_, 1, 0, 24);
      flash_attn_kernel<<<dim3(T_ / 32, H_), 256, 0, stream>>>(
          Qb, Kb, Vb, Pall + (long)i * NPOS_ * D_,
          pos_u + (long)i * D_, pos_v + (long)i * D_, Ob);
      gemm8_kernel<32, 64, false><<<dim3(384, 1, 1), 256, 0, stream>>>(
          Ob, D_, 0, WoT + i * szDD, nullptr, nullptr, D_, 0,
          bufX, nullptr, nullptr, D_, 0, bo + (long)i * D_, nullptr, nullptr,
          bufX, D_, T_, D_, D_, 1, 0, 24);
      ln_kernel<<<T_, 256, 0, stream>>>(bufX, ln2_g + (long)i * D_, ln2_b + (long)i * D_,
                                        XNb, 1e-12f, 0, 1.0f, 1);
      gemm8_kernel<32, 128, true><<<dim3(768, 1, 1), 256, 0, stream>>>(
          XNb, D_, 0, W1T + (size_t)i * D_ * FF_, nullptr, nullptr, D_, 0,
          Hb, nullptr, nullptr, FF_, 0, ff_b1 + (long)i * FF_, nullptr, nullptr,
          nullptr, 0, T_, FF_, D_, 1, 1, 24);
      gemm8_kernel<32, 64, false><<<dim3(384, 1, 1), 256, 0, stream>>>(
          Hb, FF_, 0, W2T + (size_t)i * D_ * FF_, nullptr, nullptr, FF_, 0,
          bufX, nullptr, nullptr, D_, 0, ff_b2 + (long)i * D_, nullptr, nullptr,
          bufX, D_, T_, FF_, FF_, 1, 0, 24);
    }
  } else {
    gemm5_kernel<32, 128, false><<<dim3(192, 1, 1), 256, 0, stream>>>(
        xsb, D_, 0, embed_W, nullptr, nullptr, D_, 0,
        bufT, nullptr, nullptr, D_, 0, embed_b, nullptr, nullptr,
        nullptr, 0, T_, D_, D_, 1, 0, 24);
    ln_kernel<<<T_, 256, 0, stream>>>(bufT, embed_g, embed_bt, bufX, 1e-5f, 1, 32.0f, 0);

    gemm5_kernel<128, 64, true><<<dim3(192, 1, 14), 256, 0, stream>>>(
        posT, D_, 0, Wp, nullptr, nullptr, D_, (long)szDD,
        Pall, nullptr, nullptr, D_, (long)NPOS_ * D_, nullptr, nullptr, nullptr,
        nullptr, 0, NPOS_, D_, D_, 14, 0, 12);

    for (int i = 0; i < L_; ++i) {
      ln_kernel<<<T_, 256, 0, stream>>>(bufX, ln1_g + (long)i * D_, ln1_b + (long)i * D_,
                                        XNb, 1e-12f, 0, 1.0f, 1);
      gemm5_kernel<32, 128, true><<<dim3(192, 1, 3), 256, 0, stream>>>(
          XNb, D_, 0, Wq + i * szDD, Wk + i * szDD, Wv + i * szDD, D_, 0,
          Qb, Kb, Vb, D_, 0,
          bq + (long)i * D_, bk + (long)i * D_, bv + (long)i * D_,
          nullptr, 0, T_, D_, D_, 1, 0, 24);
      flash_attn_kernel<<<dim3(T_ / 32, H_), 256, 0, stream>>>(
          Qb, Kb, Vb, Pall + (long)i * NPOS_ * D_,
          pos_u + (long)i * D_, pos_v + (long)i * D_, Ob);
      gemm5_kernel<32, 64, false><<<dim3(384, 1, 1), 256, 0, stream>>>(
          Ob, D_, 0, Wo + i * szDD, nullptr, nullptr, D_, 0,
          bufX, nullptr, nullptr, D_, 0, bo + (long)i * D_, nullptr, nullptr,
          bufX, D_, T_, D_, D_, 1, 0, 24);
      ln_kernel<<<T_, 256, 0, stream>>>(bufX, ln2_g + (long)i * D_, ln2_b + (long)i * D_,
                                        XNb, 1e-12f, 0, 1.0f, 1);
      gemm5_kernel<32, 128, true><<<dim3(768, 1, 1), 256, 0, stream>>>(
          XNb, D_, 0, ff_W1 + (size_t)i * D_ * FF_, nullptr, nullptr, FF_, 0,
          Hb, nullptr, nullptr, FF_, 0, ff_b1 + (long)i * FF_, nullptr, nullptr,
          nullptr, 0, T_, FF_, D_, 1, 1, 24);
      gemm5_kernel<32, 64, false><<<dim3(384, 1, 1), 256, 0, stream>>>(
          Hb, FF_, 0, ff_W2 + (size_t)i * D_ * FF_, nullptr, nullptr, D_, 0,
          bufX, nullptr, nullptr, D_, 0, ff_b2 + (long)i * D_, nullptr, nullptr,
          bufX, D_, T_, FF_, FF_, 1, 0, 24);
    }
  }

  ln_kernel<<<T_, 256, 0, stream>>>(bufX, after_g, after_b, out, 1e-5f, 0, 1.0f, 0);
}